// Round 1
// baseline (421.758 us; speedup 1.0000x reference)
//
#include <hip/hip_runtime.h>

#define NEG_SLOPE 0.2f

__device__ __forceinline__ float lrelu(float x){ return x > 0.f ? x : NEG_SLOPE*x; }

// ---------------- CSR build ----------------

__global__ void hist_kernel(const int* __restrict__ dst, int* __restrict__ deg, int E){
  int e = blockIdx.x*256 + threadIdx.x;
  if(e < E) atomicAdd(&deg[dst[e]], 1);
}

__global__ __launch_bounds__(1024) void scan_kernel(const int* __restrict__ deg,
                                                    int* __restrict__ row_ptr,
                                                    int* __restrict__ cursor, int N){
  __shared__ int waveSums[16];
  __shared__ int waveOff[16];
  __shared__ int sbase, schunk;
  int tid = threadIdx.x;
  int wid = tid >> 6, lane = tid & 63;
  if(tid == 0) sbase = 0;
  __syncthreads();
  for(int c0 = 0; c0 < N; c0 += 1024){
    int i = c0 + tid;
    int v = (i < N) ? deg[i] : 0;
    int s = v;
    #pragma unroll
    for(int off = 1; off < 64; off <<= 1){
      int t = __shfl_up(s, off);
      if(lane >= off) s += t;
    }
    if(lane == 63) waveSums[wid] = s;
    __syncthreads();
    if(wid == 0){
      int wv = (lane < 16) ? waveSums[lane] : 0;
      int ws2 = wv;
      #pragma unroll
      for(int off = 1; off < 16; off <<= 1){
        int t = __shfl_up(ws2, off);
        if(lane >= off) ws2 += t;
      }
      if(lane < 16) waveOff[lane] = ws2 - wv;
      if(lane == 15) schunk = ws2;
    }
    __syncthreads();
    if(i < N){
      int rp = sbase + waveOff[wid] + (s - v);   // exclusive prefix
      row_ptr[i] = rp;
      cursor[i]  = rp;
    }
    __syncthreads();
    if(tid == 0) sbase += schunk;
    __syncthreads();
  }
  if(tid == 0) row_ptr[N] = sbase;
}

__global__ void scatter_kernel(const int* __restrict__ src, const int* __restrict__ dst,
                               int* __restrict__ cursor, int* __restrict__ csr_src, int E){
  int e = blockIdx.x*256 + threadIdx.x;
  if(e < E){
    int p = atomicAdd(&cursor[dst[e]], 1);
    csr_src[p] = src[e];
  }
}

// ---------------- GEMM: C[N,FO] = A[N,128] @ W[128,FO], fp32 ----------------
// K split into chunks so static LDS stays <= 48KB.

template<int FO>
__global__ __launch_bounds__(256) void gemm_kernel(const float* __restrict__ A,
                                                   const float* __restrict__ W,
                                                   float* __restrict__ C, int N){
  constexpr int K = 128;
  constexpr int ROWS = 32;
  constexpr int KSPLIT = (FO == 128) ? 2 : 1;
  constexpr int KC = K / KSPLIT;                 // 64 or 128
  constexpr int CG = FO / 4;                     // float4 col groups: 32 or 16
  constexpr int RSTRIDE = 256 / CG;              // 8 or 16
  constexpr int RPT = ROWS / RSTRIDE;            // 4 or 2
  __shared__ float Ws[KC * FO];                  // 32KB
  __shared__ float Xs[ROWS * K];                 // 16KB

  int tid = threadIdx.x;
  int c  = tid % CG;
  int r0 = tid / CG;
  int rb = blockIdx.x * ROWS;

  // stage X rows
  for(int idx = tid; idx < ROWS*K/4; idx += 256){
    int row  = idx / (K/4);
    int col4 = idx % (K/4);
    int g = rb + row;
    float4 v = make_float4(0.f,0.f,0.f,0.f);
    if(g < N) v = ((const float4*)A)[(size_t)g*(K/4) + col4];
    ((float4*)Xs)[idx] = v;
  }

  float acc[RPT][4];
  #pragma unroll
  for(int rr=0; rr<RPT; rr++){ acc[rr][0]=0.f; acc[rr][1]=0.f; acc[rr][2]=0.f; acc[rr][3]=0.f; }

  for(int kp = 0; kp < KSPLIT; kp++){
    __syncthreads();
    for(int idx = tid; idx < KC*FO/4; idx += 256){
      ((float4*)Ws)[idx] = ((const float4*)W)[kp*(KC*FO/4) + idx];
    }
    __syncthreads();
    #pragma unroll 4
    for(int k0 = 0; k0 < KC; k0 += 4){
      float4 wv0 = *(const float4*)&Ws[(k0+0)*FO + 4*c];
      float4 wv1 = *(const float4*)&Ws[(k0+1)*FO + 4*c];
      float4 wv2 = *(const float4*)&Ws[(k0+2)*FO + 4*c];
      float4 wv3 = *(const float4*)&Ws[(k0+3)*FO + 4*c];
      #pragma unroll
      for(int rr = 0; rr < RPT; rr++){
        int r = r0 + rr*RSTRIDE;
        float4 xv = *(const float4*)&Xs[r*K + kp*KC + k0];
        acc[rr][0] += xv.x*wv0.x; acc[rr][1] += xv.x*wv0.y; acc[rr][2] += xv.x*wv0.z; acc[rr][3] += xv.x*wv0.w;
        acc[rr][0] += xv.y*wv1.x; acc[rr][1] += xv.y*wv1.y; acc[rr][2] += xv.y*wv1.z; acc[rr][3] += xv.y*wv1.w;
        acc[rr][0] += xv.z*wv2.x; acc[rr][1] += xv.z*wv2.y; acc[rr][2] += xv.z*wv2.z; acc[rr][3] += xv.z*wv2.w;
        acc[rr][0] += xv.w*wv3.x; acc[rr][1] += xv.w*wv3.y; acc[rr][2] += xv.w*wv3.z; acc[rr][3] += xv.w*wv3.w;
      }
    }
  }

  #pragma unroll
  for(int rr = 0; rr < RPT; rr++){
    int g = rb + r0 + rr*RSTRIDE;
    if(g < N){
      float4 v = make_float4(acc[rr][0], acc[rr][1], acc[rr][2], acc[rr][3]);
      ((float4*)C)[(size_t)g*CG + c] = v;
    }
  }
}

// ---------------- alpha projections: aS[i]=h[i]·a_src, aD[i]=h[i]·a_dst ----------------

template<int F>
__global__ __launch_bounds__(256) void alpha_kernel(const float* __restrict__ h,
                                                    const float* __restrict__ a_src,
                                                    const float* __restrict__ a_dst,
                                                    float* __restrict__ aS, float* __restrict__ aD, int N){
  int wid = threadIdx.x >> 6, lane = threadIdx.x & 63;
  int i = blockIdx.x*4 + wid;
  if(i >= N) return;
  float s1 = 0.f, s2 = 0.f;
  if constexpr (F == 128){
    float2 hv = *(const float2*)&h[(size_t)i*F + lane*2];
    float2 as = *(const float2*)&a_src[lane*2];
    float2 ad = *(const float2*)&a_dst[lane*2];
    s1 = hv.x*as.x + hv.y*as.y;
    s2 = hv.x*ad.x + hv.y*ad.y;
  } else {
    float hv = h[(size_t)i*F + lane];
    s1 = hv * a_src[lane];
    s2 = hv * a_dst[lane];
  }
  #pragma unroll
  for(int off = 32; off; off >>= 1){
    s1 += __shfl_xor(s1, off);
    s2 += __shfl_xor(s2, off);
  }
  if(lane == 0){ aS[i] = s1; aD[i] = s2; }
}

// ---------------- per-dst softmax + weighted aggregation ----------------
// One wave per dst node. Self-loop handled analytically. ACT: 0=relu(+bias), 1=sigmoid(+bias)

template<int F, int ACT>
__global__ __launch_bounds__(256) void agg_kernel(const float* __restrict__ h,
                                                  const float* __restrict__ aS,
                                                  const float* __restrict__ aD,
                                                  const int* __restrict__ row_ptr,
                                                  const int* __restrict__ csr_src,
                                                  const float* __restrict__ bias,
                                                  float* __restrict__ out, int N){
  int wid = threadIdx.x >> 6, lane = threadIdx.x & 63;
  int d = blockIdx.x*4 + wid;
  if(d >= N) return;
  int start = row_ptr[d], end = row_ptr[d+1];
  float aDd = aD[d];
  float e_self = lrelu(aS[d] + aDd);

  // pass 1: max
  float m = -1e30f;
  for(int i = start + lane; i < end; i += 64){
    int s = csr_src[i];
    m = fmaxf(m, lrelu(aS[s] + aDd));
  }
  #pragma unroll
  for(int off = 32; off; off >>= 1) m = fmaxf(m, __shfl_xor(m, off));
  m = fmaxf(m, e_self);

  // pass 2: sum of exp
  float ssum = 0.f;
  for(int i = start + lane; i < end; i += 64){
    int s = csr_src[i];
    ssum += expf(lrelu(aS[s] + aDd) - m);
  }
  #pragma unroll
  for(int off = 32; off; off >>= 1) ssum += __shfl_xor(ssum, off);
  ssum += expf(e_self - m);
  float inv = 1.f / ssum;

  // pass 3: weighted gather
  if constexpr (F == 128){
    int f0 = lane*2;
    float ax = 0.f, ay = 0.f;
    for(int i = start; i < end; i++){
      int s = csr_src[i];                         // broadcast load
      float wgt = expf(lrelu(aS[s] + aDd) - m) * inv;
      float2 hv = *(const float2*)&h[(size_t)s*F + f0];
      ax += wgt*hv.x; ay += wgt*hv.y;
    }
    float wself = expf(e_self - m) * inv;
    float2 hv = *(const float2*)&h[(size_t)d*F + f0];
    ax += wself*hv.x; ay += wself*hv.y;
    float2 bv = *(const float2*)&bias[f0];
    float vx = ax + bv.x, vy = ay + bv.y;
    if(ACT == 0){ vx = fmaxf(vx, 0.f); vy = fmaxf(vy, 0.f); }
    else        { vx = 1.f/(1.f + expf(-vx)); vy = 1.f/(1.f + expf(-vy)); }
    *(float2*)&out[(size_t)d*F + f0] = make_float2(vx, vy);
  } else {
    int f0 = lane;
    float a = 0.f;
    for(int i = start; i < end; i++){
      int s = csr_src[i];
      float wgt = expf(lrelu(aS[s] + aDd) - m) * inv;
      a += wgt * h[(size_t)s*F + f0];
    }
    float wself = expf(e_self - m) * inv;
    a += wself * h[(size_t)d*F + f0];
    float v = a + bias[f0];
    if(ACT == 0) v = fmaxf(v, 0.f);
    else         v = 1.f/(1.f + expf(-v));
    out[(size_t)d*F + f0] = v;
  }
}

// ---------------- launch ----------------

extern "C" void kernel_launch(void* const* d_in, const int* in_sizes, int n_in,
                              void* d_out, int out_size, void* d_ws, size_t ws_size,
                              hipStream_t stream){
  const float* x   = (const float*)d_in[0];
  const int*   ei  = (const int*)d_in[1];
  const float* W1  = (const float*)d_in[2];
  const float* a1s = (const float*)d_in[3];
  const float* a1d = (const float*)d_in[4];
  const float* b1  = (const float*)d_in[5];
  const float* W2  = (const float*)d_in[6];
  const float* a2s = (const float*)d_in[7];
  const float* a2d = (const float*)d_in[8];
  const float* b2  = (const float*)d_in[9];

  const int Fin = 128, H = 128, F2 = 64;
  int N = in_sizes[0] / Fin;
  int E = in_sizes[1] / 2;
  const int* src = ei;
  const int* dst = ei + E;

  char* w = (char*)d_ws;
  auto carve = [&](size_t bytes) -> void* {
    void* p = (void*)w;
    w += (bytes + 255) & ~(size_t)255;
    return p;
  };
  float* h1      = (float*)carve((size_t)N*H*4);   // reused as h2 later
  float* h1a     = (float*)carve((size_t)N*H*4);
  float* aS      = (float*)carve((size_t)N*4);
  float* aD      = (float*)carve((size_t)N*4);
  int*   deg     = (int*)  carve((size_t)N*4);
  int*   row_ptr = (int*)  carve((size_t)(N+1)*4);
  int*   cursor  = (int*)  carve((size_t)N*4);
  int*   csr_src = (int*)  carve((size_t)E*4);
  float* h2 = h1;
  (void)ws_size; (void)n_in; (void)out_size; (void)Fin; (void)F2;

  // CSR by destination (same graph both layers)
  hipMemsetAsync(deg, 0, (size_t)N*4, stream);
  hist_kernel<<<(E+255)/256, 256, 0, stream>>>(dst, deg, E);
  scan_kernel<<<1, 1024, 0, stream>>>(deg, row_ptr, cursor, N);
  scatter_kernel<<<(E+255)/256, 256, 0, stream>>>(src, dst, cursor, csr_src, E);

  // layer 1
  gemm_kernel<128><<<(N+31)/32, 256, 0, stream>>>(x, W1, h1, N);
  alpha_kernel<128><<<(N+3)/4, 256, 0, stream>>>(h1, a1s, a1d, aS, aD, N);
  agg_kernel<128,0><<<(N+3)/4, 256, 0, stream>>>(h1, aS, aD, row_ptr, csr_src, b1, h1a, N);

  // layer 2
  gemm_kernel<64><<<(N+31)/32, 256, 0, stream>>>(h1a, W2, h2, N);
  alpha_kernel<64><<<(N+3)/4, 256, 0, stream>>>(h2, a2s, a2d, aS, aD, N);
  agg_kernel<64,1><<<(N+3)/4, 256, 0, stream>>>(h2, aS, aD, row_ptr, csr_src, b2, (float*)d_out, N);
}

// Round 2
// 303.480 us; speedup vs baseline: 1.3897x; 1.3897x over previous
//
#include <hip/hip_runtime.h>

#define NEG_SLOPE 0.2f

__device__ __forceinline__ float lrelu(float x){ return x > 0.f ? x : NEG_SLOPE*x; }

// ---------------- CSR build ----------------

__global__ void hist_kernel(const int* __restrict__ dst, int* __restrict__ deg, int E){
  int e = blockIdx.x*256 + threadIdx.x;
  if(e < E) atomicAdd(&deg[dst[e]], 1);
}

// k1: per-block sums of 1024-element chunks
__global__ __launch_bounds__(256) void block_sums(const int* __restrict__ deg,
                                                  int* __restrict__ partials, int N){
  __shared__ int wsum[4];
  int b = blockIdx.x, tid = threadIdx.x;
  int wid = tid >> 6, lane = tid & 63;
  int i0 = b*1024 + tid*4;
  int s = 0;
  if(i0 + 3 < N){
    int4 t = *(const int4*)&deg[i0];
    s = t.x + t.y + t.z + t.w;
  } else {
    if(i0   < N) s += deg[i0];
    if(i0+1 < N) s += deg[i0+1];
    if(i0+2 < N) s += deg[i0+2];
    if(i0+3 < N) s += deg[i0+3];
  }
  #pragma unroll
  for(int off = 32; off; off >>= 1) s += __shfl_xor(s, off);
  if(lane == 0) wsum[wid] = s;
  __syncthreads();
  if(tid == 0) partials[b] = wsum[0] + wsum[1] + wsum[2] + wsum[3];
}

// k2: single-wave exclusive scan of partials (nb <= a few hundred)
__global__ void scan_partials(int* __restrict__ partials, int nb){
  int lane = threadIdx.x & 63;
  int base = 0;
  for(int c0 = 0; c0 < nb; c0 += 64){
    int i = c0 + lane;
    int v = (i < nb) ? partials[i] : 0;
    int s = v;
    #pragma unroll
    for(int off = 1; off < 64; off <<= 1){
      int t = __shfl_up(s, off);
      if(lane >= off) s += t;
    }
    if(i < nb) partials[i] = base + s - v;
    base += __shfl(s, 63);
  }
}

// k3: apply — full exclusive scan of deg -> row_ptr, cursor
__global__ __launch_bounds__(256) void scan_apply(const int* __restrict__ deg,
                                                  const int* __restrict__ partials,
                                                  int* __restrict__ row_ptr,
                                                  int* __restrict__ cursor, int N, int E){
  __shared__ int wsum[4];
  int b = blockIdx.x, tid = threadIdx.x;
  int wid = tid >> 6, lane = tid & 63;
  int i0 = b*1024 + tid*4;
  int v0=0,v1=0,v2=0,v3=0;
  if(i0 + 3 < N){
    int4 t = *(const int4*)&deg[i0];
    v0=t.x; v1=t.y; v2=t.z; v3=t.w;
  } else {
    if(i0   < N) v0 = deg[i0];
    if(i0+1 < N) v1 = deg[i0+1];
    if(i0+2 < N) v2 = deg[i0+2];
    if(i0+3 < N) v3 = deg[i0+3];
  }
  int tot = v0+v1+v2+v3;
  int s = tot;
  #pragma unroll
  for(int off = 1; off < 64; off <<= 1){
    int t = __shfl_up(s, off);
    if(lane >= off) s += t;
  }
  int texcl = s - tot;            // exclusive prefix within wave
  if(lane == 63) wsum[wid] = s;   // wave total
  __syncthreads();
  int woff = 0;
  for(int w = 0; w < wid; w++) woff += wsum[w];
  int base = partials[b] + woff + texcl;
  if(i0   < N){ row_ptr[i0]   = base;          cursor[i0]   = base; }
  if(i0+1 < N){ row_ptr[i0+1] = base+v0;       cursor[i0+1] = base+v0; }
  if(i0+2 < N){ row_ptr[i0+2] = base+v0+v1;    cursor[i0+2] = base+v0+v1; }
  if(i0+3 < N){ row_ptr[i0+3] = base+v0+v1+v2; cursor[i0+3] = base+v0+v1+v2; }
  if(b == 0 && tid == 0) row_ptr[N] = E;
}

__global__ void scatter_kernel(const int* __restrict__ src, const int* __restrict__ dst,
                               int* __restrict__ cursor, int* __restrict__ csr_src,
                               int* __restrict__ csr_dst, int E){
  int e = blockIdx.x*256 + threadIdx.x;
  if(e < E){
    int d = dst[e];
    int p = atomicAdd(&cursor[d], 1);
    csr_src[p] = src[e];
    csr_dst[p] = d;
  }
}

// ---------------- GEMM: C[N,FO] = A[N,128] @ W[128,FO], fp32 ----------------

template<int FO>
__global__ __launch_bounds__(256) void gemm_kernel(const float* __restrict__ A,
                                                   const float* __restrict__ W,
                                                   float* __restrict__ C, int N){
  constexpr int K = 128;
  constexpr int ROWS = 32;
  constexpr int KSPLIT = (FO == 128) ? 2 : 1;
  constexpr int KC = K / KSPLIT;                 // 64 or 128
  constexpr int CG = FO / 4;                     // float4 col groups: 32 or 16
  constexpr int RSTRIDE = 256 / CG;              // 8 or 16
  constexpr int RPT = ROWS / RSTRIDE;            // 4 or 2
  __shared__ float Ws[KC * FO];                  // 32KB
  __shared__ float Xs[ROWS * K];                 // 16KB

  int tid = threadIdx.x;
  int c  = tid % CG;
  int r0 = tid / CG;
  int rb = blockIdx.x * ROWS;

  for(int idx = tid; idx < ROWS*K/4; idx += 256){
    int row  = idx / (K/4);
    int col4 = idx % (K/4);
    int g = rb + row;
    float4 v = make_float4(0.f,0.f,0.f,0.f);
    if(g < N) v = ((const float4*)A)[(size_t)g*(K/4) + col4];
    ((float4*)Xs)[idx] = v;
  }

  float acc[RPT][4];
  #pragma unroll
  for(int rr=0; rr<RPT; rr++){ acc[rr][0]=0.f; acc[rr][1]=0.f; acc[rr][2]=0.f; acc[rr][3]=0.f; }

  for(int kp = 0; kp < KSPLIT; kp++){
    __syncthreads();
    for(int idx = tid; idx < KC*FO/4; idx += 256){
      ((float4*)Ws)[idx] = ((const float4*)W)[kp*(KC*FO/4) + idx];
    }
    __syncthreads();
    #pragma unroll 4
    for(int k0 = 0; k0 < KC; k0 += 4){
      float4 wv0 = *(const float4*)&Ws[(k0+0)*FO + 4*c];
      float4 wv1 = *(const float4*)&Ws[(k0+1)*FO + 4*c];
      float4 wv2 = *(const float4*)&Ws[(k0+2)*FO + 4*c];
      float4 wv3 = *(const float4*)&Ws[(k0+3)*FO + 4*c];
      #pragma unroll
      for(int rr = 0; rr < RPT; rr++){
        int r = r0 + rr*RSTRIDE;
        float4 xv = *(const float4*)&Xs[r*K + kp*KC + k0];
        acc[rr][0] += xv.x*wv0.x; acc[rr][1] += xv.x*wv0.y; acc[rr][2] += xv.x*wv0.z; acc[rr][3] += xv.x*wv0.w;
        acc[rr][0] += xv.y*wv1.x; acc[rr][1] += xv.y*wv1.y; acc[rr][2] += xv.y*wv1.z; acc[rr][3] += xv.y*wv1.w;
        acc[rr][0] += xv.z*wv2.x; acc[rr][1] += xv.z*wv2.y; acc[rr][2] += xv.z*wv2.z; acc[rr][3] += xv.z*wv2.w;
        acc[rr][0] += xv.w*wv3.x; acc[rr][1] += xv.w*wv3.y; acc[rr][2] += xv.w*wv3.z; acc[rr][3] += xv.w*wv3.w;
      }
    }
  }

  #pragma unroll
  for(int rr = 0; rr < RPT; rr++){
    int g = rb + r0 + rr*RSTRIDE;
    if(g < N){
      float4 v = make_float4(acc[rr][0], acc[rr][1], acc[rr][2], acc[rr][3]);
      ((float4*)C)[(size_t)g*CG + c] = v;
    }
  }
}

// ---------------- alpha projections ----------------

template<int F>
__global__ __launch_bounds__(256) void alpha_kernel(const float* __restrict__ h,
                                                    const float* __restrict__ a_src,
                                                    const float* __restrict__ a_dst,
                                                    float* __restrict__ aS, float* __restrict__ aD, int N){
  int wid = threadIdx.x >> 6, lane = threadIdx.x & 63;
  int i = blockIdx.x*4 + wid;
  if(i >= N) return;
  float s1 = 0.f, s2 = 0.f;
  if constexpr (F == 128){
    float2 hv = *(const float2*)&h[(size_t)i*F + lane*2];
    float2 as = *(const float2*)&a_src[lane*2];
    float2 ad = *(const float2*)&a_dst[lane*2];
    s1 = hv.x*as.x + hv.y*as.y;
    s2 = hv.x*ad.x + hv.y*ad.y;
  } else {
    float hv = h[(size_t)i*F + lane];
    s1 = hv * a_src[lane];
    s2 = hv * a_dst[lane];
  }
  #pragma unroll
  for(int off = 32; off; off >>= 1){
    s1 += __shfl_xor(s1, off);
    s2 += __shfl_xor(s2, off);
  }
  if(lane == 0){ aS[i] = s1; aD[i] = s2; }
}

// ---------------- per-edge raw attention logits (CSR order, coalesced write) ----------------

__global__ void ew_kernel(const int* __restrict__ csr_src, const int* __restrict__ csr_dst,
                          const float* __restrict__ aS, const float* __restrict__ aD,
                          float* __restrict__ ew, int E){
  int i = blockIdx.x*256 + threadIdx.x;
  if(i < E) ew[i] = lrelu(aS[csr_src[i]] + aD[csr_dst[i]]);
}

// ---------------- per-dst softmax + weighted aggregation ----------------
// One wave per dst. Sub-wave edge parallelism in the gather; no transcendentals in the loop.

template<int F, int ACT>
__global__ __launch_bounds__(256) void agg_kernel(const float* __restrict__ h,
                                                  float* ew,  // logits in, unnormalized exp out (in-place)
                                                  const int* __restrict__ row_ptr,
                                                  const int* __restrict__ csr_src,
                                                  const float* __restrict__ aS,
                                                  const float* __restrict__ aD,
                                                  const float* __restrict__ bias,
                                                  float* __restrict__ out, int N){
  int wid = threadIdx.x >> 6, lane = threadIdx.x & 63;
  int d = blockIdx.x*4 + wid;
  if(d >= N) return;
  int start = row_ptr[d], end = row_ptr[d+1];
  float e_self = lrelu(aS[d] + aD[d]);

  // pass 1: max over logits (coalesced)
  float m = e_self;
  for(int i = start + lane; i < end; i += 64) m = fmaxf(m, ew[i]);
  #pragma unroll
  for(int off = 32; off; off >>= 1) m = fmaxf(m, __shfl_xor(m, off));

  // pass 2: exp in place (lane-parallel), sum
  float ssum = 0.f;
  for(int i = start + lane; i < end; i += 64){
    float pp = expf(ew[i] - m);
    ew[i] = pp;
    ssum += pp;
  }
  #pragma unroll
  for(int off = 32; off; off >>= 1) ssum += __shfl_xor(ssum, off);
  float pself = expf(e_self - m);
  ssum += pself;
  float inv = 1.f / ssum;

  // pass 3: gather, EPW edges per iteration, float4 per lane
  constexpr int LPE = F / 4;       // lanes per edge: 32 (F=128) or 16 (F=64)
  constexpr int EPW = 64 / LPE;    // edges per wave-iter: 2 or 4
  int sub = lane / LPE;
  int l2  = lane % LPE;
  float ax = 0.f, ay = 0.f, az = 0.f, aw = 0.f;
  for(int i = start; i < end; i += EPW){
    int j = i + sub;
    if(j < end){
      int s = csr_src[j];
      float wgt = ew[j];
      float4 hv = *(const float4*)&h[(size_t)s*F + l2*4];
      ax += wgt*hv.x; ay += wgt*hv.y; az += wgt*hv.z; aw += wgt*hv.w;
    }
  }
  if(sub == 0){
    float4 hv = *(const float4*)&h[(size_t)d*F + l2*4];
    ax += pself*hv.x; ay += pself*hv.y; az += pself*hv.z; aw += pself*hv.w;
  }
  // combine sub-waves
  if(EPW == 4){
    ax += __shfl_xor(ax, 16); ay += __shfl_xor(ay, 16);
    az += __shfl_xor(az, 16); aw += __shfl_xor(aw, 16);
  }
  ax += __shfl_xor(ax, 32); ay += __shfl_xor(ay, 32);
  az += __shfl_xor(az, 32); aw += __shfl_xor(aw, 32);

  if(lane < LPE){
    float4 bv = *(const float4*)&bias[lane*4];
    float vx = ax*inv + bv.x, vy = ay*inv + bv.y, vz = az*inv + bv.z, vw = aw*inv + bv.w;
    if(ACT == 0){
      vx = fmaxf(vx, 0.f); vy = fmaxf(vy, 0.f); vz = fmaxf(vz, 0.f); vw = fmaxf(vw, 0.f);
    } else {
      vx = 1.f/(1.f + expf(-vx)); vy = 1.f/(1.f + expf(-vy));
      vz = 1.f/(1.f + expf(-vz)); vw = 1.f/(1.f + expf(-vw));
    }
    *(float4*)&out[(size_t)d*F + lane*4] = make_float4(vx, vy, vz, vw);
  }
}

// ---------------- launch ----------------

extern "C" void kernel_launch(void* const* d_in, const int* in_sizes, int n_in,
                              void* d_out, int out_size, void* d_ws, size_t ws_size,
                              hipStream_t stream){
  const float* x   = (const float*)d_in[0];
  const int*   ei  = (const int*)d_in[1];
  const float* W1  = (const float*)d_in[2];
  const float* a1s = (const float*)d_in[3];
  const float* a1d = (const float*)d_in[4];
  const float* b1  = (const float*)d_in[5];
  const float* W2  = (const float*)d_in[6];
  const float* a2s = (const float*)d_in[7];
  const float* a2d = (const float*)d_in[8];
  const float* b2  = (const float*)d_in[9];

  const int Fin = 128, H = 128;
  int N = in_sizes[0] / Fin;
  int E = in_sizes[1] / 2;
  const int* src = ei;
  const int* dst = ei + E;

  char* w = (char*)d_ws;
  auto carve = [&](size_t bytes) -> void* {
    void* p = (void*)w;
    w += (bytes + 255) & ~(size_t)255;
    return p;
  };
  float* h1      = (float*)carve((size_t)N*H*4);   // reused as h2
  float* h1a     = (float*)carve((size_t)N*H*4);
  float* aS      = (float*)carve((size_t)N*4);
  float* aD      = (float*)carve((size_t)N*4);
  int*   deg     = (int*)  carve((size_t)N*4);
  int*   row_ptr = (int*)  carve((size_t)(N+1)*4);
  int*   cursor  = (int*)  carve((size_t)N*4);
  int*   partials= (int*)  carve((size_t)1024*4);
  int*   csr_src = (int*)  carve((size_t)E*4);
  int*   csr_dst = (int*)  carve((size_t)E*4);
  float* ew      = (float*)carve((size_t)E*4);
  float* h2 = h1;
  (void)ws_size; (void)n_in; (void)out_size;

  int nb = (N + 1023) / 1024;

  // CSR by destination (same graph both layers)
  hipMemsetAsync(deg, 0, (size_t)N*4, stream);
  hist_kernel<<<(E+255)/256, 256, 0, stream>>>(dst, deg, E);
  block_sums<<<nb, 256, 0, stream>>>(deg, partials, N);
  scan_partials<<<1, 64, 0, stream>>>(partials, nb);
  scan_apply<<<nb, 256, 0, stream>>>(deg, partials, row_ptr, cursor, N, E);
  scatter_kernel<<<(E+255)/256, 256, 0, stream>>>(src, dst, cursor, csr_src, csr_dst, E);

  // layer 1
  gemm_kernel<128><<<(N+31)/32, 256, 0, stream>>>(x, W1, h1, N);
  alpha_kernel<128><<<(N+3)/4, 256, 0, stream>>>(h1, a1s, a1d, aS, aD, N);
  ew_kernel<<<(E+255)/256, 256, 0, stream>>>(csr_src, csr_dst, aS, aD, ew, E);
  agg_kernel<128,0><<<(N+3)/4, 256, 0, stream>>>(h1, ew, row_ptr, csr_src, aS, aD, b1, h1a, N);

  // layer 2
  gemm_kernel<64><<<(N+31)/32, 256, 0, stream>>>(h1a, W2, h2, N);
  alpha_kernel<64><<<(N+3)/4, 256, 0, stream>>>(h2, a2s, a2d, aS, aD, N);
  ew_kernel<<<(E+255)/256, 256, 0, stream>>>(csr_src, csr_dst, aS, aD, ew, E);
  agg_kernel<64,1><<<(N+3)/4, 256, 0, stream>>>(h2, ew, row_ptr, csr_src, aS, aD, b2, (float*)d_out, N);
}

// Round 3
// 275.069 us; speedup vs baseline: 1.5333x; 1.1033x over previous
//
#include <hip/hip_runtime.h>

#define NEG_SLOPE 0.2f

__device__ __forceinline__ float lrelu(float x){ return x > 0.f ? x : NEG_SLOPE*x; }

// ---------------- CSR build ----------------

__global__ void hist_kernel(const int* __restrict__ dst, int* __restrict__ deg, int E){
  int e = blockIdx.x*256 + threadIdx.x;
  if(e < E) atomicAdd(&deg[dst[e]], 1);
}

// k1: per-block sums of 1024-element chunks
__global__ __launch_bounds__(256) void block_sums(const int* __restrict__ deg,
                                                  int* __restrict__ partials, int N){
  __shared__ int wsum[4];
  int b = blockIdx.x, tid = threadIdx.x;
  int wid = tid >> 6, lane = tid & 63;
  int i0 = b*1024 + tid*4;
  int s = 0;
  if(i0 + 3 < N){
    int4 t = *(const int4*)&deg[i0];
    s = t.x + t.y + t.z + t.w;
  } else {
    if(i0   < N) s += deg[i0];
    if(i0+1 < N) s += deg[i0+1];
    if(i0+2 < N) s += deg[i0+2];
    if(i0+3 < N) s += deg[i0+3];
  }
  #pragma unroll
  for(int off = 32; off; off >>= 1) s += __shfl_xor(s, off);
  if(lane == 0) wsum[wid] = s;
  __syncthreads();
  if(tid == 0) partials[b] = wsum[0] + wsum[1] + wsum[2] + wsum[3];
}

// k2: single-wave exclusive scan of partials
__global__ void scan_partials(int* __restrict__ partials, int nb){
  int lane = threadIdx.x & 63;
  int base = 0;
  for(int c0 = 0; c0 < nb; c0 += 64){
    int i = c0 + lane;
    int v = (i < nb) ? partials[i] : 0;
    int s = v;
    #pragma unroll
    for(int off = 1; off < 64; off <<= 1){
      int t = __shfl_up(s, off);
      if(lane >= off) s += t;
    }
    if(i < nb) partials[i] = base + s - v;
    base += __shfl(s, 63);
  }
}

// k3: apply — full exclusive scan of deg -> row_ptr, cursor
__global__ __launch_bounds__(256) void scan_apply(const int* __restrict__ deg,
                                                  const int* __restrict__ partials,
                                                  int* __restrict__ row_ptr,
                                                  int* __restrict__ cursor, int N, int E){
  __shared__ int wsum[4];
  int b = blockIdx.x, tid = threadIdx.x;
  int wid = tid >> 6, lane = tid & 63;
  int i0 = b*1024 + tid*4;
  int v0=0,v1=0,v2=0,v3=0;
  if(i0 + 3 < N){
    int4 t = *(const int4*)&deg[i0];
    v0=t.x; v1=t.y; v2=t.z; v3=t.w;
  } else {
    if(i0   < N) v0 = deg[i0];
    if(i0+1 < N) v1 = deg[i0+1];
    if(i0+2 < N) v2 = deg[i0+2];
    if(i0+3 < N) v3 = deg[i0+3];
  }
  int tot = v0+v1+v2+v3;
  int s = tot;
  #pragma unroll
  for(int off = 1; off < 64; off <<= 1){
    int t = __shfl_up(s, off);
    if(lane >= off) s += t;
  }
  int texcl = s - tot;
  if(lane == 63) wsum[wid] = s;
  __syncthreads();
  int woff = 0;
  for(int w = 0; w < wid; w++) woff += wsum[w];
  int base = partials[b] + woff + texcl;
  if(i0   < N){ row_ptr[i0]   = base;          cursor[i0]   = base; }
  if(i0+1 < N){ row_ptr[i0+1] = base+v0;       cursor[i0+1] = base+v0; }
  if(i0+2 < N){ row_ptr[i0+2] = base+v0+v1;    cursor[i0+2] = base+v0+v1; }
  if(i0+3 < N){ row_ptr[i0+3] = base+v0+v1+v2; cursor[i0+3] = base+v0+v1+v2; }
  if(b == 0 && tid == 0) row_ptr[N] = E;
}

__global__ void scatter_kernel(const int* __restrict__ src, const int* __restrict__ dst,
                               int* __restrict__ cursor, int* __restrict__ csr_src, int E){
  int e = blockIdx.x*256 + threadIdx.x;
  if(e < E){
    int p = atomicAdd(&cursor[dst[e]], 1);
    csr_src[p] = src[e];
  }
}

// ---------------- GEMM: C[N,FO] = A[N,128] @ W[128,FO], fp32 ----------------

template<int FO>
__global__ __launch_bounds__(256) void gemm_kernel(const float* __restrict__ A,
                                                   const float* __restrict__ W,
                                                   float* __restrict__ C, int N){
  constexpr int K = 128;
  constexpr int ROWS = 32;
  constexpr int KSPLIT = (FO == 128) ? 2 : 1;
  constexpr int KC = K / KSPLIT;
  constexpr int CG = FO / 4;
  constexpr int RSTRIDE = 256 / CG;
  constexpr int RPT = ROWS / RSTRIDE;
  __shared__ float Ws[KC * FO];
  __shared__ float Xs[ROWS * K];

  int tid = threadIdx.x;
  int c  = tid % CG;
  int r0 = tid / CG;
  int rb = blockIdx.x * ROWS;

  for(int idx = tid; idx < ROWS*K/4; idx += 256){
    int row  = idx / (K/4);
    int col4 = idx % (K/4);
    int g = rb + row;
    float4 v = make_float4(0.f,0.f,0.f,0.f);
    if(g < N) v = ((const float4*)A)[(size_t)g*(K/4) + col4];
    ((float4*)Xs)[idx] = v;
  }

  float acc[RPT][4];
  #pragma unroll
  for(int rr=0; rr<RPT; rr++){ acc[rr][0]=0.f; acc[rr][1]=0.f; acc[rr][2]=0.f; acc[rr][3]=0.f; }

  for(int kp = 0; kp < KSPLIT; kp++){
    __syncthreads();
    for(int idx = tid; idx < KC*FO/4; idx += 256){
      ((float4*)Ws)[idx] = ((const float4*)W)[kp*(KC*FO/4) + idx];
    }
    __syncthreads();
    #pragma unroll 4
    for(int k0 = 0; k0 < KC; k0 += 4){
      float4 wv0 = *(const float4*)&Ws[(k0+0)*FO + 4*c];
      float4 wv1 = *(const float4*)&Ws[(k0+1)*FO + 4*c];
      float4 wv2 = *(const float4*)&Ws[(k0+2)*FO + 4*c];
      float4 wv3 = *(const float4*)&Ws[(k0+3)*FO + 4*c];
      #pragma unroll
      for(int rr = 0; rr < RPT; rr++){
        int r = r0 + rr*RSTRIDE;
        float4 xv = *(const float4*)&Xs[r*K + kp*KC + k0];
        acc[rr][0] += xv.x*wv0.x; acc[rr][1] += xv.x*wv0.y; acc[rr][2] += xv.x*wv0.z; acc[rr][3] += xv.x*wv0.w;
        acc[rr][0] += xv.y*wv1.x; acc[rr][1] += xv.y*wv1.y; acc[rr][2] += xv.y*wv1.z; acc[rr][3] += xv.y*wv1.w;
        acc[rr][0] += xv.z*wv2.x; acc[rr][1] += xv.z*wv2.y; acc[rr][2] += xv.z*wv2.z; acc[rr][3] += xv.z*wv2.w;
        acc[rr][0] += xv.w*wv3.x; acc[rr][1] += xv.w*wv3.y; acc[rr][2] += xv.w*wv3.z; acc[rr][3] += xv.w*wv3.w;
      }
    }
  }

  #pragma unroll
  for(int rr = 0; rr < RPT; rr++){
    int g = rb + r0 + rr*RSTRIDE;
    if(g < N){
      float4 v = make_float4(acc[rr][0], acc[rr][1], acc[rr][2], acc[rr][3]);
      ((float4*)C)[(size_t)g*CG + c] = v;
    }
  }
}

// ---------------- alpha projections ----------------

template<int F>
__global__ __launch_bounds__(256) void alpha_kernel(const float* __restrict__ h,
                                                    const float* __restrict__ a_src,
                                                    const float* __restrict__ a_dst,
                                                    float* __restrict__ aS, float* __restrict__ aD, int N){
  int wid = threadIdx.x >> 6, lane = threadIdx.x & 63;
  int i = blockIdx.x*4 + wid;
  if(i >= N) return;
  float s1 = 0.f, s2 = 0.f;
  if constexpr (F == 128){
    float2 hv = *(const float2*)&h[(size_t)i*F + lane*2];
    float2 as = *(const float2*)&a_src[lane*2];
    float2 ad = *(const float2*)&a_dst[lane*2];
    s1 = hv.x*as.x + hv.y*as.y;
    s2 = hv.x*ad.x + hv.y*ad.y;
  } else {
    float hv = h[(size_t)i*F + lane];
    s1 = hv * a_src[lane];
    s2 = hv * a_dst[lane];
  }
  #pragma unroll
  for(int off = 32; off; off >>= 1){
    s1 += __shfl_xor(s1, off);
    s2 += __shfl_xor(s2, off);
  }
  if(lane == 0){ aS[i] = s1; aD[i] = s2; }
}

// ---------------- per-dst softmax + weighted aggregation ----------------
// One wave per dst. Row indices+logits live in registers (lane i owns edge start+i);
// gather loop gets (src, weight) via __shfl — the only memory ops are the h gathers,
// which are independent and unrolled for MLP depth. Logits computed in-kernel from aS
// (L2-resident, 200KB) — no ew[] array, no csr_dst.

template<int F, int ACT>
__global__ __launch_bounds__(256) void agg_kernel(const float* __restrict__ h,
                                                  const int* __restrict__ row_ptr,
                                                  const int* __restrict__ csr_src,
                                                  const float* __restrict__ aS,
                                                  const float* __restrict__ aD,
                                                  const float* __restrict__ bias,
                                                  float* __restrict__ out, int N){
  int wid = threadIdx.x >> 6, lane = threadIdx.x & 63;
  int d = blockIdx.x*4 + wid;
  if(d >= N) return;
  int start = row_ptr[d], end = row_ptr[d+1];
  int deg = end - start;
  float aDd = aD[d];
  float e_self = lrelu(aS[d] + aDd);

  // chunk 0 (up to 64 edges) cached in registers: lane i owns edge start+i
  int i0 = start + lane;
  bool val0 = (i0 < end);
  int idx0 = val0 ? csr_src[i0] : 0;
  float w0 = val0 ? lrelu(aS[idx0] + aDd) : -1e30f;

  // max (incl. rare extra chunks)
  float m = fmaxf(e_self, w0);
  for(int i = start + 64 + lane; i < end; i += 64){
    int s = csr_src[i];
    m = fmaxf(m, lrelu(aS[s] + aDd));
  }
  #pragma unroll
  for(int off = 32; off; off >>= 1) m = fmaxf(m, __shfl_xor(m, off));

  float p0 = val0 ? expf(w0 - m) : 0.f;
  float pself = expf(e_self - m);
  float ssum_l = p0 + (lane == 0 ? pself : 0.f);

  constexpr int LPE = F / 4;       // lanes per edge: 32 (F=128) or 16 (F=64)
  constexpr int EPW = 64 / LPE;    // edges per wave-iter: 2 or 4
  int sub = lane / LPE;
  int l2  = lane % LPE;
  float ax = 0.f, ay = 0.f, az = 0.f, aw = 0.f;

  int c0deg = deg < 64 ? deg : 64;
  #pragma unroll 4
  for(int jj = sub; jj < c0deg; jj += EPW){
    int   s   = __shfl(idx0, jj);
    float wgt = __shfl(p0, jj);
    float4 hv = *(const float4*)&h[(size_t)s*F + l2*4];
    ax += wgt*hv.x; ay += wgt*hv.y; az += wgt*hv.z; aw += wgt*hv.w;
  }

  // rare extra chunks (deg > 64)
  for(int cb = start + 64; cb < end; cb += 64){
    int i = cb + lane;
    bool v = (i < end);
    int idx = v ? csr_src[i] : 0;
    float p = v ? expf(lrelu(aS[idx] + aDd) - m) : 0.f;
    ssum_l += p;
    int cd = (end - cb) < 64 ? (end - cb) : 64;
    for(int jj = sub; jj < cd; jj += EPW){
      int   s   = __shfl(idx, jj);
      float wgt = __shfl(p, jj);
      float4 hv = *(const float4*)&h[(size_t)s*F + l2*4];
      ax += wgt*hv.x; ay += wgt*hv.y; az += wgt*hv.z; aw += wgt*hv.w;
    }
  }

  // self-loop contribution
  if(sub == 0){
    float4 hv = *(const float4*)&h[(size_t)d*F + l2*4];
    ax += pself*hv.x; ay += pself*hv.y; az += pself*hv.z; aw += pself*hv.w;
  }

  // sum reduce (each edge counted once across lanes)
  #pragma unroll
  for(int off = 32; off; off >>= 1) ssum_l += __shfl_xor(ssum_l, off);
  float inv = 1.f / ssum_l;

  // combine sub-waves
  if(EPW == 4){
    ax += __shfl_xor(ax, 16); ay += __shfl_xor(ay, 16);
    az += __shfl_xor(az, 16); aw += __shfl_xor(aw, 16);
  }
  ax += __shfl_xor(ax, 32); ay += __shfl_xor(ay, 32);
  az += __shfl_xor(az, 32); aw += __shfl_xor(aw, 32);

  if(lane < LPE){
    float4 bv = *(const float4*)&bias[lane*4];
    float vx = ax*inv + bv.x, vy = ay*inv + bv.y, vz = az*inv + bv.z, vw = aw*inv + bv.w;
    if(ACT == 0){
      vx = fmaxf(vx, 0.f); vy = fmaxf(vy, 0.f); vz = fmaxf(vz, 0.f); vw = fmaxf(vw, 0.f);
    } else {
      vx = 1.f/(1.f + expf(-vx)); vy = 1.f/(1.f + expf(-vy));
      vz = 1.f/(1.f + expf(-vz)); vw = 1.f/(1.f + expf(-vw));
    }
    *(float4*)&out[(size_t)d*F + lane*4] = make_float4(vx, vy, vz, vw);
  }
}

// ---------------- launch ----------------

extern "C" void kernel_launch(void* const* d_in, const int* in_sizes, int n_in,
                              void* d_out, int out_size, void* d_ws, size_t ws_size,
                              hipStream_t stream){
  const float* x   = (const float*)d_in[0];
  const int*   ei  = (const int*)d_in[1];
  const float* W1  = (const float*)d_in[2];
  const float* a1s = (const float*)d_in[3];
  const float* a1d = (const float*)d_in[4];
  const float* b1  = (const float*)d_in[5];
  const float* W2  = (const float*)d_in[6];
  const float* a2s = (const float*)d_in[7];
  const float* a2d = (const float*)d_in[8];
  const float* b2  = (const float*)d_in[9];

  const int Fin = 128, H = 128;
  int N = in_sizes[0] / Fin;
  int E = in_sizes[1] / 2;
  const int* src = ei;
  const int* dst = ei + E;

  char* w = (char*)d_ws;
  auto carve = [&](size_t bytes) -> void* {
    void* p = (void*)w;
    w += (bytes + 255) & ~(size_t)255;
    return p;
  };
  float* h1      = (float*)carve((size_t)N*H*4);   // reused as h2
  float* h1a     = (float*)carve((size_t)N*H*4);
  float* aS      = (float*)carve((size_t)N*4);
  float* aD      = (float*)carve((size_t)N*4);
  int*   deg     = (int*)  carve((size_t)N*4);
  int*   row_ptr = (int*)  carve((size_t)(N+1)*4);
  int*   cursor  = (int*)  carve((size_t)N*4);
  int*   partials= (int*)  carve((size_t)1024*4);
  int*   csr_src = (int*)  carve((size_t)E*4);
  float* h2 = h1;
  (void)ws_size; (void)n_in; (void)out_size;

  int nb = (N + 1023) / 1024;

  // CSR by destination (same graph both layers)
  hipMemsetAsync(deg, 0, (size_t)N*4, stream);
  hist_kernel<<<(E+255)/256, 256, 0, stream>>>(dst, deg, E);
  block_sums<<<nb, 256, 0, stream>>>(deg, partials, N);
  scan_partials<<<1, 64, 0, stream>>>(partials, nb);
  scan_apply<<<nb, 256, 0, stream>>>(deg, partials, row_ptr, cursor, N, E);
  scatter_kernel<<<(E+255)/256, 256, 0, stream>>>(src, dst, cursor, csr_src, E);

  // layer 1
  gemm_kernel<128><<<(N+31)/32, 256, 0, stream>>>(x, W1, h1, N);
  alpha_kernel<128><<<(N+3)/4, 256, 0, stream>>>(h1, a1s, a1d, aS, aD, N);
  agg_kernel<128,0><<<(N+3)/4, 256, 0, stream>>>(h1, row_ptr, csr_src, aS, aD, b1, h1a, N);

  // layer 2
  gemm_kernel<64><<<(N+31)/32, 256, 0, stream>>>(h1a, W2, h2, N);
  alpha_kernel<64><<<(N+3)/4, 256, 0, stream>>>(h2, a2s, a2d, aS, aD, N);
  agg_kernel<64,1><<<(N+3)/4, 256, 0, stream>>>(h2, row_ptr, csr_src, aS, aD, b2, (float*)d_out, N);
}

// Round 4
// 243.306 us; speedup vs baseline: 1.7334x; 1.1305x over previous
//
#include <hip/hip_runtime.h>
#include <hip/hip_fp16.h>

#define NEG_SLOPE 0.2f

__device__ __forceinline__ float lrelu(float x){ return x > 0.f ? x : NEG_SLOPE*x; }

// ---------------- CSR build ----------------

__global__ void hist_kernel(const int* __restrict__ dst, int* __restrict__ deg, int E){
  int e = blockIdx.x*256 + threadIdx.x;
  if(e < E) atomicAdd(&deg[dst[e]], 1);
}

__global__ __launch_bounds__(256) void block_sums(const int* __restrict__ deg,
                                                  int* __restrict__ partials, int N){
  __shared__ int wsum[4];
  int b = blockIdx.x, tid = threadIdx.x;
  int wid = tid >> 6, lane = tid & 63;
  int i0 = b*1024 + tid*4;
  int s = 0;
  if(i0 + 3 < N){
    int4 t = *(const int4*)&deg[i0];
    s = t.x + t.y + t.z + t.w;
  } else {
    if(i0   < N) s += deg[i0];
    if(i0+1 < N) s += deg[i0+1];
    if(i0+2 < N) s += deg[i0+2];
    if(i0+3 < N) s += deg[i0+3];
  }
  #pragma unroll
  for(int off = 32; off; off >>= 1) s += __shfl_xor(s, off);
  if(lane == 0) wsum[wid] = s;
  __syncthreads();
  if(tid == 0) partials[b] = wsum[0] + wsum[1] + wsum[2] + wsum[3];
}

__global__ void scan_partials(int* __restrict__ partials, int nb){
  int lane = threadIdx.x & 63;
  int base = 0;
  for(int c0 = 0; c0 < nb; c0 += 64){
    int i = c0 + lane;
    int v = (i < nb) ? partials[i] : 0;
    int s = v;
    #pragma unroll
    for(int off = 1; off < 64; off <<= 1){
      int t = __shfl_up(s, off);
      if(lane >= off) s += t;
    }
    if(i < nb) partials[i] = base + s - v;
    base += __shfl(s, 63);
  }
}

__global__ __launch_bounds__(256) void scan_apply(const int* __restrict__ deg,
                                                  const int* __restrict__ partials,
                                                  int* __restrict__ row_ptr,
                                                  int* __restrict__ cursor, int N, int E){
  __shared__ int wsum[4];
  int b = blockIdx.x, tid = threadIdx.x;
  int wid = tid >> 6, lane = tid & 63;
  int i0 = b*1024 + tid*4;
  int v0=0,v1=0,v2=0,v3=0;
  if(i0 + 3 < N){
    int4 t = *(const int4*)&deg[i0];
    v0=t.x; v1=t.y; v2=t.z; v3=t.w;
  } else {
    if(i0   < N) v0 = deg[i0];
    if(i0+1 < N) v1 = deg[i0+1];
    if(i0+2 < N) v2 = deg[i0+2];
    if(i0+3 < N) v3 = deg[i0+3];
  }
  int tot = v0+v1+v2+v3;
  int s = tot;
  #pragma unroll
  for(int off = 1; off < 64; off <<= 1){
    int t = __shfl_up(s, off);
    if(lane >= off) s += t;
  }
  int texcl = s - tot;
  if(lane == 63) wsum[wid] = s;
  __syncthreads();
  int woff = 0;
  for(int w = 0; w < wid; w++) woff += wsum[w];
  int base = partials[b] + woff + texcl;
  if(i0   < N){ row_ptr[i0]   = base;          cursor[i0]   = base; }
  if(i0+1 < N){ row_ptr[i0+1] = base+v0;       cursor[i0+1] = base+v0; }
  if(i0+2 < N){ row_ptr[i0+2] = base+v0+v1;    cursor[i0+2] = base+v0+v1; }
  if(i0+3 < N){ row_ptr[i0+3] = base+v0+v1+v2; cursor[i0+3] = base+v0+v1+v2; }
  if(b == 0 && tid == 0) row_ptr[N] = E;
}

__global__ void scatter_kernel(const int* __restrict__ src, const int* __restrict__ dst,
                               int* __restrict__ cursor, int* __restrict__ csr_src, int E){
  int e = blockIdx.x*256 + threadIdx.x;
  if(e < E){
    int p = atomicAdd(&cursor[dst[e]], 1);
    csr_src[p] = src[e];
  }
}

// ---------------- GEMM: h16[N,FO] = fp16(A[N,128] @ W[128,FO]); aS/aD fused epilogue ----------------

template<int FO>
__global__ __launch_bounds__(256) void gemm_kernel(const float* __restrict__ A,
                                                   const float* __restrict__ W,
                                                   const float* __restrict__ a_src,
                                                   const float* __restrict__ a_dst,
                                                   __half* __restrict__ h16,
                                                   float* __restrict__ aS,
                                                   float* __restrict__ aD, int N){
  constexpr int K = 128;
  constexpr int ROWS = 32;
  constexpr int KSPLIT = (FO == 128) ? 2 : 1;
  constexpr int KC = K / KSPLIT;
  constexpr int CG = FO / 4;                     // 32 or 16 lanes per row
  constexpr int RSTRIDE = 256 / CG;              // 8 or 16
  constexpr int RPT = ROWS / RSTRIDE;            // 4 or 2
  __shared__ float Ws[KC * FO];
  __shared__ float Xs[ROWS * K];

  int tid = threadIdx.x;
  int c  = tid % CG;
  int r0 = tid / CG;
  int rb = blockIdx.x * ROWS;

  for(int idx = tid; idx < ROWS*K/4; idx += 256){
    int row  = idx / (K/4);
    int col4 = idx % (K/4);
    int g = rb + row;
    float4 v = make_float4(0.f,0.f,0.f,0.f);
    if(g < N) v = ((const float4*)A)[(size_t)g*(K/4) + col4];
    ((float4*)Xs)[idx] = v;
  }

  float acc[RPT][4];
  #pragma unroll
  for(int rr=0; rr<RPT; rr++){ acc[rr][0]=0.f; acc[rr][1]=0.f; acc[rr][2]=0.f; acc[rr][3]=0.f; }

  for(int kp = 0; kp < KSPLIT; kp++){
    __syncthreads();
    for(int idx = tid; idx < KC*FO/4; idx += 256){
      ((float4*)Ws)[idx] = ((const float4*)W)[kp*(KC*FO/4) + idx];
    }
    __syncthreads();
    #pragma unroll 4
    for(int k0 = 0; k0 < KC; k0 += 4){
      float4 wv0 = *(const float4*)&Ws[(k0+0)*FO + 4*c];
      float4 wv1 = *(const float4*)&Ws[(k0+1)*FO + 4*c];
      float4 wv2 = *(const float4*)&Ws[(k0+2)*FO + 4*c];
      float4 wv3 = *(const float4*)&Ws[(k0+3)*FO + 4*c];
      #pragma unroll
      for(int rr = 0; rr < RPT; rr++){
        int r = r0 + rr*RSTRIDE;
        float4 xv = *(const float4*)&Xs[r*K + kp*KC + k0];
        acc[rr][0] += xv.x*wv0.x; acc[rr][1] += xv.x*wv0.y; acc[rr][2] += xv.x*wv0.z; acc[rr][3] += xv.x*wv0.w;
        acc[rr][0] += xv.y*wv1.x; acc[rr][1] += xv.y*wv1.y; acc[rr][2] += xv.y*wv1.z; acc[rr][3] += xv.y*wv1.w;
        acc[rr][0] += xv.z*wv2.x; acc[rr][1] += xv.z*wv2.y; acc[rr][2] += xv.z*wv2.z; acc[rr][3] += xv.z*wv2.w;
        acc[rr][0] += xv.w*wv3.x; acc[rr][1] += xv.w*wv3.y; acc[rr][2] += xv.w*wv3.z; acc[rr][3] += xv.w*wv3.w;
      }
    }
  }

  // epilogue: fp16 store + fused alpha projections (reduce over the CG lanes of each row)
  float4 asv = *(const float4*)&a_src[4*c];
  float4 adv = *(const float4*)&a_dst[4*c];
  #pragma unroll
  for(int rr = 0; rr < RPT; rr++){
    int g = rb + r0 + rr*RSTRIDE;
    float s1 = acc[rr][0]*asv.x + acc[rr][1]*asv.y + acc[rr][2]*asv.z + acc[rr][3]*asv.w;
    float s2 = acc[rr][0]*adv.x + acc[rr][1]*adv.y + acc[rr][2]*adv.z + acc[rr][3]*adv.w;
    #pragma unroll
    for(int off = CG/2; off; off >>= 1){
      s1 += __shfl_xor(s1, off);
      s2 += __shfl_xor(s2, off);
    }
    if(g < N){
      union { __half2 h2[2]; uint2 u; } pk;
      pk.h2[0] = __floats2half2_rn(acc[rr][0], acc[rr][1]);
      pk.h2[1] = __floats2half2_rn(acc[rr][2], acc[rr][3]);
      *(uint2*)&h16[(size_t)g*FO + 4*c] = pk.u;
      if(c == 0){ aS[g] = s1; aD[g] = s2; }
    }
  }
}

// ---------------- per-dst softmax + weighted aggregation (fp16 payload) ----------------
// One wave per dst; chunk-0 indices/logits in registers; gather gets (src,wgt) via shfl.
// fp16 rows: F=128 -> 16 lanes/edge (8 feats each), 4 edges/iter; F=64 -> 8 lanes/edge, 8 edges/iter.

template<int F, int ACT>
__global__ __launch_bounds__(256) void agg_kernel(const __half* __restrict__ h16,
                                                  const int* __restrict__ row_ptr,
                                                  const int* __restrict__ csr_src,
                                                  const float* __restrict__ aS,
                                                  const float* __restrict__ aD,
                                                  const float* __restrict__ bias,
                                                  float* __restrict__ out, int N){
  int wid = threadIdx.x >> 6, lane = threadIdx.x & 63;
  int d = blockIdx.x*4 + wid;
  if(d >= N) return;
  int start = row_ptr[d], end = row_ptr[d+1];
  int deg = end - start;
  float aDd = aD[d];
  float e_self = lrelu(aS[d] + aDd);

  // chunk 0 (up to 64 edges) in registers
  int i0 = start + lane;
  bool val0 = (i0 < end);
  int idx0 = val0 ? csr_src[i0] : 0;
  float w0 = val0 ? lrelu(aS[idx0] + aDd) : -1e30f;

  float m = fmaxf(e_self, w0);
  for(int i = start + 64 + lane; i < end; i += 64){
    int s = csr_src[i];
    m = fmaxf(m, lrelu(aS[s] + aDd));
  }
  #pragma unroll
  for(int off = 32; off; off >>= 1) m = fmaxf(m, __shfl_xor(m, off));

  float p0 = val0 ? expf(w0 - m) : 0.f;
  float pself = expf(e_self - m);
  float ssum_l = p0 + (lane == 0 ? pself : 0.f);

  constexpr int LPE = F / 8;       // lanes per edge: 16 (F=128) or 8 (F=64)
  constexpr int EPW = 64 / LPE;    // edges per wave-iter: 4 or 8
  int sub = lane / LPE;
  int l2  = lane % LPE;
  float acc8[8];
  #pragma unroll
  for(int q = 0; q < 8; q++) acc8[q] = 0.f;

  auto gat = [&](int s, float wgt){
    union { float4 f4; __half2 h2[4]; } u;
    u.f4 = *(const float4*)&h16[(size_t)s*F + l2*8];
    #pragma unroll
    for(int q = 0; q < 4; q++){
      float2 f = __half22float2(u.h2[q]);
      acc8[2*q]   += wgt*f.x;
      acc8[2*q+1] += wgt*f.y;
    }
  };

  int c0deg = deg < 64 ? deg : 64;
  #pragma unroll 4
  for(int jj = sub; jj < c0deg; jj += EPW){
    int   s   = __shfl(idx0, jj);
    float wgt = __shfl(p0, jj);
    gat(s, wgt);
  }

  // rare extra chunks (deg > 64)
  for(int cb = start + 64; cb < end; cb += 64){
    int i = cb + lane;
    bool v = (i < end);
    int idx = v ? csr_src[i] : 0;
    float p = v ? expf(lrelu(aS[idx] + aDd) - m) : 0.f;
    ssum_l += p;
    int cd = (end - cb) < 64 ? (end - cb) : 64;
    for(int jj = sub; jj < cd; jj += EPW){
      int   s   = __shfl(idx, jj);
      float wgt = __shfl(p, jj);
      gat(s, wgt);
    }
  }

  // self-loop
  if(sub == 0) gat(d, pself);

  #pragma unroll
  for(int off = 32; off; off >>= 1) ssum_l += __shfl_xor(ssum_l, off);
  float inv = 1.f / ssum_l;

  // combine sub-waves
  #pragma unroll
  for(int off = LPE; off < 64; off <<= 1){
    #pragma unroll
    for(int q = 0; q < 8; q++) acc8[q] += __shfl_xor(acc8[q], off);
  }

  if(lane < LPE){
    float4 bv0 = *(const float4*)&bias[lane*8];
    float4 bv1 = *(const float4*)&bias[lane*8 + 4];
    float v[8];
    v[0]=acc8[0]*inv+bv0.x; v[1]=acc8[1]*inv+bv0.y; v[2]=acc8[2]*inv+bv0.z; v[3]=acc8[3]*inv+bv0.w;
    v[4]=acc8[4]*inv+bv1.x; v[5]=acc8[5]*inv+bv1.y; v[6]=acc8[6]*inv+bv1.z; v[7]=acc8[7]*inv+bv1.w;
    #pragma unroll
    for(int q = 0; q < 8; q++){
      if(ACT == 0) v[q] = fmaxf(v[q], 0.f);
      else         v[q] = 1.f/(1.f + expf(-v[q]));
    }
    *(float4*)&out[(size_t)d*F + lane*8]     = make_float4(v[0],v[1],v[2],v[3]);
    *(float4*)&out[(size_t)d*F + lane*8 + 4] = make_float4(v[4],v[5],v[6],v[7]);
  }
}

// ---------------- launch ----------------

extern "C" void kernel_launch(void* const* d_in, const int* in_sizes, int n_in,
                              void* d_out, int out_size, void* d_ws, size_t ws_size,
                              hipStream_t stream){
  const float* x   = (const float*)d_in[0];
  const int*   ei  = (const int*)d_in[1];
  const float* W1  = (const float*)d_in[2];
  const float* a1s = (const float*)d_in[3];
  const float* a1d = (const float*)d_in[4];
  const float* b1  = (const float*)d_in[5];
  const float* W2  = (const float*)d_in[6];
  const float* a2s = (const float*)d_in[7];
  const float* a2d = (const float*)d_in[8];
  const float* b2  = (const float*)d_in[9];

  const int Fin = 128, H = 128, F2 = 64;
  int N = in_sizes[0] / Fin;
  int E = in_sizes[1] / 2;
  const int* src = ei;
  const int* dst = ei + E;

  char* w = (char*)d_ws;
  auto carve = [&](size_t bytes) -> void* {
    void* p = (void*)w;
    w += (bytes + 255) & ~(size_t)255;
    return p;
  };
  __half* h1_16  = (__half*)carve((size_t)N*H*2);
  __half* h2_16  = (__half*)carve((size_t)N*F2*2);
  float*  h1a    = (float*)carve((size_t)N*H*4);
  float*  aS     = (float*)carve((size_t)N*4);
  float*  aD     = (float*)carve((size_t)N*4);
  int*    deg    = (int*)  carve((size_t)N*4);
  int*    row_ptr= (int*)  carve((size_t)(N+1)*4);
  int*    cursor = (int*)  carve((size_t)N*4);
  int*    partials=(int*)  carve((size_t)1024*4);
  int*    csr_src= (int*)  carve((size_t)E*4);
  (void)ws_size; (void)n_in; (void)out_size;

  int nb = (N + 1023) / 1024;

  // CSR by destination (same graph both layers)
  hipMemsetAsync(deg, 0, (size_t)N*4, stream);
  hist_kernel<<<(E+255)/256, 256, 0, stream>>>(dst, deg, E);
  block_sums<<<nb, 256, 0, stream>>>(deg, partials, N);
  scan_partials<<<1, 64, 0, stream>>>(partials, nb);
  scan_apply<<<nb, 256, 0, stream>>>(deg, partials, row_ptr, cursor, N, E);
  scatter_kernel<<<(E+255)/256, 256, 0, stream>>>(src, dst, cursor, csr_src, E);

  // layer 1
  gemm_kernel<128><<<(N+31)/32, 256, 0, stream>>>(x, W1, a1s, a1d, h1_16, aS, aD, N);
  agg_kernel<128,0><<<(N+3)/4, 256, 0, stream>>>(h1_16, row_ptr, csr_src, aS, aD, b1, h1a, N);

  // layer 2
  gemm_kernel<64><<<(N+31)/32, 256, 0, stream>>>(h1a, W2, a2s, a2d, h2_16, aS, aD, N);
  agg_kernel<64,1><<<(N+3)/4, 256, 0, stream>>>(h2_16, row_ptr, csr_src, aS, aD, b2, (float*)d_out, N);
}

// Round 6
// 233.843 us; speedup vs baseline: 1.8036x; 1.0405x over previous
//
#include <hip/hip_runtime.h>
#include <hip/hip_fp16.h>

#define NEG_SLOPE 0.2f

typedef _Float16 half8 __attribute__((ext_vector_type(8)));
typedef float floatx4 __attribute__((ext_vector_type(4)));

__device__ __forceinline__ float lrelu(float x){ return x > 0.f ? x : NEG_SLOPE*x; }

// ---------------- CSR build (XCD-partitioned: blockIdx%8 -> dst range) ----------------

__global__ __launch_bounds__(256) void hist_kernel(const int* __restrict__ dst,
                                                   int* __restrict__ deg,
                                                   int E, int npart){
  int part = blockIdx.x & 7;
  int w    = blockIdx.x >> 3;
  int lo = part * npart, hi = lo + npart;
  int stride = (gridDim.x >> 3) * 256;
  for(int e = w*256 + threadIdx.x; e < E; e += stride){
    int d = dst[e];
    if(d >= lo && d < hi) atomicAdd(&deg[d], 1);
  }
}

__global__ __launch_bounds__(256) void scatter_kernel(const int* __restrict__ src,
                                                      const int* __restrict__ dst,
                                                      int* __restrict__ cursor,
                                                      int* __restrict__ csr_src,
                                                      int E, int npart){
  int part = blockIdx.x & 7;
  int w    = blockIdx.x >> 3;
  int lo = part * npart, hi = lo + npart;
  int stride = (gridDim.x >> 3) * 256;
  for(int e = w*256 + threadIdx.x; e < E; e += stride){
    int d = dst[e];
    if(d >= lo && d < hi){
      int p = atomicAdd(&cursor[d], 1);
      csr_src[p] = src[e];
    }
  }
}

__global__ __launch_bounds__(256) void block_sums(const int* __restrict__ deg,
                                                  int* __restrict__ partials, int N){
  __shared__ int wsum[4];
  int b = blockIdx.x, tid = threadIdx.x;
  int wid = tid >> 6, lane = tid & 63;
  int i0 = b*1024 + tid*4;
  int s = 0;
  if(i0 + 3 < N){
    int4 t = *(const int4*)&deg[i0];
    s = t.x + t.y + t.z + t.w;
  } else {
    if(i0   < N) s += deg[i0];
    if(i0+1 < N) s += deg[i0+1];
    if(i0+2 < N) s += deg[i0+2];
    if(i0+3 < N) s += deg[i0+3];
  }
  #pragma unroll
  for(int off = 32; off; off >>= 1) s += __shfl_xor(s, off);
  if(lane == 0) wsum[wid] = s;
  __syncthreads();
  if(tid == 0) partials[b] = wsum[0] + wsum[1] + wsum[2] + wsum[3];
}

__global__ void scan_partials(int* __restrict__ partials, int nb){
  int lane = threadIdx.x & 63;
  int base = 0;
  for(int c0 = 0; c0 < nb; c0 += 64){
    int i = c0 + lane;
    int v = (i < nb) ? partials[i] : 0;
    int s = v;
    #pragma unroll
    for(int off = 1; off < 64; off <<= 1){
      int t = __shfl_up(s, off);
      if(lane >= off) s += t;
    }
    if(i < nb) partials[i] = base + s - v;
    base += __shfl(s, 63);
  }
}

__global__ __launch_bounds__(256) void scan_apply(const int* __restrict__ deg,
                                                  const int* __restrict__ partials,
                                                  int* __restrict__ row_ptr,
                                                  int* __restrict__ cursor, int N, int E){
  __shared__ int wsum[4];
  int b = blockIdx.x, tid = threadIdx.x;
  int wid = tid >> 6, lane = tid & 63;
  int i0 = b*1024 + tid*4;
  int v0=0,v1=0,v2=0,v3=0;
  if(i0 + 3 < N){
    int4 t = *(const int4*)&deg[i0];
    v0=t.x; v1=t.y; v2=t.z; v3=t.w;
  } else {
    if(i0   < N) v0 = deg[i0];
    if(i0+1 < N) v1 = deg[i0+1];
    if(i0+2 < N) v2 = deg[i0+2];
    if(i0+3 < N) v3 = deg[i0+3];
  }
  int tot = v0+v1+v2+v3;
  int s = tot;
  #pragma unroll
  for(int off = 1; off < 64; off <<= 1){
    int t = __shfl_up(s, off);
    if(lane >= off) s += t;
  }
  int texcl = s - tot;
  if(lane == 63) wsum[wid] = s;
  __syncthreads();
  int woff = 0;
  for(int w = 0; w < wid; w++) woff += wsum[w];
  int base = partials[b] + woff + texcl;
  if(i0   < N){ row_ptr[i0]   = base;          cursor[i0]   = base; }
  if(i0+1 < N){ row_ptr[i0+1] = base+v0;       cursor[i0+1] = base+v0; }
  if(i0+2 < N){ row_ptr[i0+2] = base+v0+v1;    cursor[i0+2] = base+v0+v1; }
  if(i0+3 < N){ row_ptr[i0+3] = base+v0+v1+v2; cursor[i0+3] = base+v0+v1+v2; }
  if(b == 0 && tid == 0) row_ptr[N] = E;
}

// ---------------- W transpose to fp16 hi/lo (once per launch) ----------------
// W1 [128][128] -> W1h/W1l [c][k]; W2 [128][64] -> W2h/W2l [c][k]

__global__ void transpose_w(const float* __restrict__ W1, const float* __restrict__ W2,
                            _Float16* __restrict__ W1h, _Float16* __restrict__ W1l,
                            _Float16* __restrict__ W2h, _Float16* __restrict__ W2l){
  int i = blockIdx.x*256 + threadIdx.x;
  if(i < 128*128){
    int k = i >> 7, c = i & 127;
    float f = W1[i];
    _Float16 h = (_Float16)f;
    W1h[c*128 + k] = h;
    W1l[c*128 + k] = (_Float16)(f - (float)h);
  } else if(i < 128*128 + 128*64){
    int j = i - 128*128;
    int k = j >> 6, c = j & 63;
    float f = W2[j];
    _Float16 h = (_Float16)f;
    W2h[c*128 + k] = h;
    W2l[c*128 + k] = (_Float16)(f - (float)h);
  }
}

// ---------------- MFMA GEMM (LDS-free, hi/lo compensated) ----------------
// h16[N,FO] = fp16(A[N,128] @ W[128,FO]); aS/aD fused epilogue, fp32-accurate acc.
// 4 waves/block, 16 rows/wave. A fragments 32B/lane from global; B fragments 16B/lane
// from L2-resident W^T hi/lo. acc += a_hi*b_hi + a_lo*b_hi + a_hi*b_lo.

template<int FO>
__global__ __launch_bounds__(256) void gemm_mfma(const float* __restrict__ A,
                                                 const _Float16* __restrict__ Wh,
                                                 const _Float16* __restrict__ Wl,
                                                 const float* __restrict__ a_src,
                                                 const float* __restrict__ a_dst,
                                                 __half* __restrict__ h16,
                                                 float* __restrict__ aS,
                                                 float* __restrict__ aD, int N){
  constexpr int CT = FO / 16;                 // col tiles: 8 or 4
  int tid = threadIdx.x;
  int w = tid >> 6, lane = tid & 63;
  int l15 = lane & 15;
  int q4  = lane >> 4;                        // 0..3: k-chunk of the fragment

  int arow = blockIdx.x*64 + w*16 + l15;      // A row this lane loads
  bool rv = arow < N;

  // A fragments hi/lo: lane holds A[arow][kb*32 + q4*8 .. +7]
  half8 ah[4], al[4];
  #pragma unroll
  for(int kb = 0; kb < 4; kb++){
    float4 f0 = make_float4(0.f,0.f,0.f,0.f), f1 = f0;
    if(rv){
      f0 = ((const float4*)A)[(size_t)arow*32 + kb*8 + q4*2];
      f1 = ((const float4*)A)[(size_t)arow*32 + kb*8 + q4*2 + 1];
    }
    float fv[8] = {f0.x,f0.y,f0.z,f0.w,f1.x,f1.y,f1.z,f1.w};
    #pragma unroll
    for(int q = 0; q < 8; q++){
      _Float16 h = (_Float16)fv[q];
      ah[kb][q] = h;
      al[kb][q] = (_Float16)(fv[q] - (float)h);
    }
  }

  floatx4 acc[CT];
  #pragma unroll
  for(int ct = 0; ct < CT; ct++) acc[ct] = (floatx4){0.f,0.f,0.f,0.f};

  #pragma unroll
  for(int ct = 0; ct < CT; ct++){
    int wrow = ct*16 + l15;
    #pragma unroll
    for(int kb = 0; kb < 4; kb++){
      int off = wrow*128 + kb*32 + q4*8;
      half8 bh = *(const half8*)&Wh[off];
      half8 bl = *(const half8*)&Wl[off];
      acc[ct] = __builtin_amdgcn_mfma_f32_16x16x32_f16(ah[kb], bh, acc[ct], 0, 0, 0);
      acc[ct] = __builtin_amdgcn_mfma_f32_16x16x32_f16(al[kb], bh, acc[ct], 0, 0, 0);
      acc[ct] = __builtin_amdgcn_mfma_f32_16x16x32_f16(ah[kb], bl, acc[ct], 0, 0, 0);
    }
  }

  // epilogue: fused alpha projections + fp16 store
  // C/D: col = ct*16 + l15, row = q4*4 + r (within the wave's 16-row tile)
  float s1[4] = {0.f,0.f,0.f,0.f}, s2[4] = {0.f,0.f,0.f,0.f};
  #pragma unroll
  for(int ct = 0; ct < CT; ct++){
    int col = ct*16 + l15;
    float as_c = a_src[col], ad_c = a_dst[col];
    #pragma unroll
    for(int r = 0; r < 4; r++){
      float v = acc[ct][r];
      s1[r] += v*as_c; s2[r] += v*ad_c;
    }
  }
  #pragma unroll
  for(int r = 0; r < 4; r++){
    #pragma unroll
    for(int off = 1; off < 16; off <<= 1){
      s1[r] += __shfl_xor(s1[r], off);
      s2[r] += __shfl_xor(s2[r], off);
    }
  }
  int rowbase = blockIdx.x*64 + w*16 + q4*4;
  if(l15 == 0){
    #pragma unroll
    for(int r = 0; r < 4; r++){
      int g = rowbase + r;
      if(g < N){ aS[g] = s1[r]; aD[g] = s2[r]; }
    }
  }
  #pragma unroll
  for(int ct = 0; ct < CT; ct++){
    #pragma unroll
    for(int r = 0; r < 4; r++){
      int g = rowbase + r;
      if(g < N) h16[(size_t)g*FO + ct*16 + l15] = __float2half(acc[ct][r]);
    }
  }
}

// ---------------- per-dst softmax + weighted aggregation (fp16 payload) ----------------

template<int F, int ACT>
__global__ __launch_bounds__(256) void agg_kernel(const __half* __restrict__ h16,
                                                  const int* __restrict__ row_ptr,
                                                  const int* __restrict__ csr_src,
                                                  const float* __restrict__ aS,
                                                  const float* __restrict__ aD,
                                                  const float* __restrict__ bias,
                                                  float* __restrict__ out, int N){
  int wid = threadIdx.x >> 6, lane = threadIdx.x & 63;
  int d = blockIdx.x*4 + wid;
  if(d >= N) return;
  int start = row_ptr[d], end = row_ptr[d+1];
  int deg = end - start;
  float aDd = aD[d];
  float e_self = lrelu(aS[d] + aDd);

  int i0 = start + lane;
  bool val0 = (i0 < end);
  int idx0 = val0 ? csr_src[i0] : 0;
  float w0 = val0 ? lrelu(aS[idx0] + aDd) : -1e30f;

  float m = fmaxf(e_self, w0);
  for(int i = start + 64 + lane; i < end; i += 64){
    int s = csr_src[i];
    m = fmaxf(m, lrelu(aS[s] + aDd));
  }
  #pragma unroll
  for(int off = 32; off; off >>= 1) m = fmaxf(m, __shfl_xor(m, off));

  float p0 = val0 ? expf(w0 - m) : 0.f;
  float pself = expf(e_self - m);
  float ssum_l = p0 + (lane == 0 ? pself : 0.f);

  constexpr int LPE = F / 8;
  constexpr int EPW = 64 / LPE;
  int sub = lane / LPE;
  int l2  = lane % LPE;
  float acc8[8];
  #pragma unroll
  for(int q = 0; q < 8; q++) acc8[q] = 0.f;

  auto gat = [&](int s, float wgt){
    union { float4 f4; __half2 h2[4]; } u;
    u.f4 = *(const float4*)&h16[(size_t)s*F + l2*8];
    #pragma unroll
    for(int q = 0; q < 4; q++){
      float2 f = __half22float2(u.h2[q]);
      acc8[2*q]   += wgt*f.x;
      acc8[2*q+1] += wgt*f.y;
    }
  };

  int c0deg = deg < 64 ? deg : 64;
  #pragma unroll 4
  for(int jj = sub; jj < c0deg; jj += EPW){
    int   s   = __shfl(idx0, jj);
    float wgt = __shfl(p0, jj);
    gat(s, wgt);
  }

  for(int cb = start + 64; cb < end; cb += 64){
    int i = cb + lane;
    bool v = (i < end);
    int idx = v ? csr_src[i] : 0;
    float p = v ? expf(lrelu(aS[idx] + aDd) - m) : 0.f;
    ssum_l += p;
    int cd = (end - cb) < 64 ? (end - cb) : 64;
    for(int jj = sub; jj < cd; jj += EPW){
      int   s   = __shfl(idx, jj);
      float wgt = __shfl(p, jj);
      gat(s, wgt);
    }
  }

  if(sub == 0) gat(d, pself);

  #pragma unroll
  for(int off = 32; off; off >>= 1) ssum_l += __shfl_xor(ssum_l, off);
  float inv = 1.f / ssum_l;

  #pragma unroll
  for(int off = LPE; off < 64; off <<= 1){
    #pragma unroll
    for(int q = 0; q < 8; q++) acc8[q] += __shfl_xor(acc8[q], off);
  }

  if(lane < LPE){
    float4 bv0 = *(const float4*)&bias[lane*8];
    float4 bv1 = *(const float4*)&bias[lane*8 + 4];
    float v[8];
    v[0]=acc8[0]*inv+bv0.x; v[1]=acc8[1]*inv+bv0.y; v[2]=acc8[2]*inv+bv0.z; v[3]=acc8[3]*inv+bv0.w;
    v[4]=acc8[4]*inv+bv1.x; v[5]=acc8[5]*inv+bv1.y; v[6]=acc8[6]*inv+bv1.z; v[7]=acc8[7]*inv+bv1.w;
    #pragma unroll
    for(int q = 0; q < 8; q++){
      if(ACT == 0) v[q] = fmaxf(v[q], 0.f);
      else         v[q] = 1.f/(1.f + expf(-v[q]));
    }
    *(float4*)&out[(size_t)d*F + lane*8]     = make_float4(v[0],v[1],v[2],v[3]);
    *(float4*)&out[(size_t)d*F + lane*8 + 4] = make_float4(v[4],v[5],v[6],v[7]);
  }
}

// ---------------- launch ----------------

extern "C" void kernel_launch(void* const* d_in, const int* in_sizes, int n_in,
                              void* d_out, int out_size, void* d_ws, size_t ws_size,
                              hipStream_t stream){
  const float* x   = (const float*)d_in[0];
  const int*   ei  = (const int*)d_in[1];
  const float* W1  = (const float*)d_in[2];
  const float* a1s = (const float*)d_in[3];
  const float* a1d = (const float*)d_in[4];
  const float* b1  = (const float*)d_in[5];
  const float* W2  = (const float*)d_in[6];
  const float* a2s = (const float*)d_in[7];
  const float* a2d = (const float*)d_in[8];
  const float* b2  = (const float*)d_in[9];

  const int Fin = 128, H = 128, F2 = 64;
  int N = in_sizes[0] / Fin;
  int E = in_sizes[1] / 2;
  const int* src = ei;
  const int* dst = ei + E;

  char* w = (char*)d_ws;
  auto carve = [&](size_t bytes) -> void* {
    void* p = (void*)w;
    w += (bytes + 255) & ~(size_t)255;
    return p;
  };
  __half*    h1_16  = (__half*)carve((size_t)N*H*2);
  __half*    h2_16  = (__half*)carve((size_t)N*F2*2);
  float*     h1a    = (float*)carve((size_t)N*H*4);
  float*     aS     = (float*)carve((size_t)N*4);
  float*     aD     = (float*)carve((size_t)N*4);
  int*       deg    = (int*)  carve((size_t)N*4);
  int*       row_ptr= (int*)  carve((size_t)(N+1)*4);
  int*       cursor = (int*)  carve((size_t)N*4);
  int*       partials=(int*)  carve((size_t)1024*4);
  int*       csr_src= (int*)  carve((size_t)E*4);
  _Float16*  W1h    = (_Float16*)carve((size_t)128*128*2);
  _Float16*  W1l    = (_Float16*)carve((size_t)128*128*2);
  _Float16*  W2h    = (_Float16*)carve((size_t)64*128*2);
  _Float16*  W2l    = (_Float16*)carve((size_t)64*128*2);
  (void)ws_size; (void)n_in; (void)out_size;

  int nb = (N + 1023) / 1024;
  int npart = (N + 7) / 8;

  // CSR by destination (XCD-partitioned hist/scatter)
  hipMemsetAsync(deg, 0, (size_t)N*4, stream);
  transpose_w<<<96, 256, 0, stream>>>(W1, W2, W1h, W1l, W2h, W2l);
  hist_kernel<<<512, 256, 0, stream>>>(dst, deg, E, npart);
  block_sums<<<nb, 256, 0, stream>>>(deg, partials, N);
  scan_partials<<<1, 64, 0, stream>>>(partials, nb);
  scan_apply<<<nb, 256, 0, stream>>>(deg, partials, row_ptr, cursor, N, E);
  scatter_kernel<<<512, 256, 0, stream>>>(src, dst, cursor, csr_src, E, npart);

  // layer 1
  gemm_mfma<128><<<(N+63)/64, 256, 0, stream>>>(x, W1h, W1l, a1s, a1d, h1_16, aS, aD, N);
  agg_kernel<128,0><<<(N+3)/4, 256, 0, stream>>>(h1_16, row_ptr, csr_src, aS, aD, b1, h1a, N);

  // layer 2
  gemm_mfma<64><<<(N+63)/64, 256, 0, stream>>>(h1a, W2h, W2l, a2s, a2d, h2_16, aS, aD, N);
  agg_kernel<64,1><<<(N+3)/4, 256, 0, stream>>>(h2_16, row_ptr, csr_src, aS, aD, b2, (float*)d_out, N);
}

// Round 7
// 227.742 us; speedup vs baseline: 1.8519x; 1.0268x over previous
//
#include <hip/hip_runtime.h>
#include <hip/hip_fp16.h>

#define NEG_SLOPE 0.2f

typedef _Float16 half8 __attribute__((ext_vector_type(8)));
typedef float floatx4 __attribute__((ext_vector_type(4)));

__device__ __forceinline__ float lrelu(float x){ return x > 0.f ? x : NEG_SLOPE*x; }

// ---------------- CSR build (XCD-partitioned: blockIdx%8 -> dst range) ----------------

__global__ __launch_bounds__(256) void hist_kernel(const int* __restrict__ dst,
                                                   int* __restrict__ deg,
                                                   int E, int npart){
  int part = blockIdx.x & 7;
  int w    = blockIdx.x >> 3;
  int lo = part * npart, hi = lo + npart;
  int stride = (gridDim.x >> 3) * 256;
  for(int e = w*256 + threadIdx.x; e < E; e += stride){
    int d = __builtin_nontemporal_load(&dst[e]);
    if(d >= lo && d < hi) atomicAdd(&deg[d], 1);
  }
}

__global__ __launch_bounds__(256) void scatter_kernel(const int* __restrict__ src,
                                                      const int* __restrict__ dst,
                                                      int* __restrict__ cursor,
                                                      int* __restrict__ csr_src,
                                                      int E, int npart){
  int part = blockIdx.x & 7;
  int w    = blockIdx.x >> 3;
  int lo = part * npart, hi = lo + npart;
  int stride = (gridDim.x >> 3) * 256;
  for(int e = w*256 + threadIdx.x; e < E; e += stride){
    int d = __builtin_nontemporal_load(&dst[e]);
    if(d >= lo && d < hi){
      int sv = __builtin_nontemporal_load(&src[e]);
      int p = atomicAdd(&cursor[d], 1);
      csr_src[p] = sv;
    }
  }
}

__global__ __launch_bounds__(256) void block_sums(const int* __restrict__ deg,
                                                  int* __restrict__ partials, int N){
  __shared__ int wsum[4];
  int b = blockIdx.x, tid = threadIdx.x;
  int wid = tid >> 6, lane = tid & 63;
  int i0 = b*1024 + tid*4;
  int s = 0;
  if(i0 + 3 < N){
    int4 t = *(const int4*)&deg[i0];
    s = t.x + t.y + t.z + t.w;
  } else {
    if(i0   < N) s += deg[i0];
    if(i0+1 < N) s += deg[i0+1];
    if(i0+2 < N) s += deg[i0+2];
    if(i0+3 < N) s += deg[i0+3];
  }
  #pragma unroll
  for(int off = 32; off; off >>= 1) s += __shfl_xor(s, off);
  if(lane == 0) wsum[wid] = s;
  __syncthreads();
  if(tid == 0) partials[b] = wsum[0] + wsum[1] + wsum[2] + wsum[3];
}

__global__ void scan_partials(int* __restrict__ partials, int nb){
  int lane = threadIdx.x & 63;
  int base = 0;
  for(int c0 = 0; c0 < nb; c0 += 64){
    int i = c0 + lane;
    int v = (i < nb) ? partials[i] : 0;
    int s = v;
    #pragma unroll
    for(int off = 1; off < 64; off <<= 1){
      int t = __shfl_up(s, off);
      if(lane >= off) s += t;
    }
    if(i < nb) partials[i] = base + s - v;
    base += __shfl(s, 63);
  }
}

__global__ __launch_bounds__(256) void scan_apply(const int* __restrict__ deg,
                                                  const int* __restrict__ partials,
                                                  int* __restrict__ row_ptr,
                                                  int* __restrict__ cursor, int N, int E){
  __shared__ int wsum[4];
  int b = blockIdx.x, tid = threadIdx.x;
  int wid = tid >> 6, lane = tid & 63;
  int i0 = b*1024 + tid*4;
  int v0=0,v1=0,v2=0,v3=0;
  if(i0 + 3 < N){
    int4 t = *(const int4*)&deg[i0];
    v0=t.x; v1=t.y; v2=t.z; v3=t.w;
  } else {
    if(i0   < N) v0 = deg[i0];
    if(i0+1 < N) v1 = deg[i0+1];
    if(i0+2 < N) v2 = deg[i0+2];
    if(i0+3 < N) v3 = deg[i0+3];
  }
  int tot = v0+v1+v2+v3;
  int s = tot;
  #pragma unroll
  for(int off = 1; off < 64; off <<= 1){
    int t = __shfl_up(s, off);
    if(lane >= off) s += t;
  }
  int texcl = s - tot;
  if(lane == 63) wsum[wid] = s;
  __syncthreads();
  int woff = 0;
  for(int w = 0; w < wid; w++) woff += wsum[w];
  int base = partials[b] + woff + texcl;
  if(i0   < N){ row_ptr[i0]   = base;          cursor[i0]   = base; }
  if(i0+1 < N){ row_ptr[i0+1] = base+v0;       cursor[i0+1] = base+v0; }
  if(i0+2 < N){ row_ptr[i0+2] = base+v0+v1;    cursor[i0+2] = base+v0+v1; }
  if(i0+3 < N){ row_ptr[i0+3] = base+v0+v1+v2; cursor[i0+3] = base+v0+v1+v2; }
  if(b == 0 && tid == 0) row_ptr[N] = E;
}

// ---------------- W transpose to fp16 hi/lo (once per launch) ----------------

__global__ void transpose_w(const float* __restrict__ W1, const float* __restrict__ W2,
                            _Float16* __restrict__ W1h, _Float16* __restrict__ W1l,
                            _Float16* __restrict__ W2h, _Float16* __restrict__ W2l){
  int i = blockIdx.x*256 + threadIdx.x;
  if(i < 128*128){
    int k = i >> 7, c = i & 127;
    float f = W1[i];
    _Float16 h = (_Float16)f;
    W1h[c*128 + k] = h;
    W1l[c*128 + k] = (_Float16)(f - (float)h);
  } else if(i < 128*128 + 128*64){
    int j = i - 128*128;
    int k = j >> 6, c = j & 63;
    float f = W2[j];
    _Float16 h = (_Float16)f;
    W2h[c*128 + k] = h;
    W2l[c*128 + k] = (_Float16)(f - (float)h);
  }
}

// ---------------- MFMA GEMM (LDS-free, hi/lo compensated) ----------------
// AHALF=0: A fp32, split hi/lo in-register, 3 MFMAs/tile. AHALF=1: A fp16 exact, 2 MFMAs.

template<int FO, int AHALF>
__global__ __launch_bounds__(256) void gemm_mfma(const void* __restrict__ Av,
                                                 const _Float16* __restrict__ Wh,
                                                 const _Float16* __restrict__ Wl,
                                                 const float* __restrict__ a_src,
                                                 const float* __restrict__ a_dst,
                                                 __half* __restrict__ h16,
                                                 float* __restrict__ aS,
                                                 float* __restrict__ aD, int N){
  constexpr int CT = FO / 16;
  int tid = threadIdx.x;
  int w = tid >> 6, lane = tid & 63;
  int l15 = lane & 15;
  int q4  = lane >> 4;

  int arow = blockIdx.x*64 + w*16 + l15;
  bool rv = arow < N;

  half8 ah[4], al[4];
  if constexpr (AHALF){
    const _Float16* A = (const _Float16*)Av;
    #pragma unroll
    for(int kb = 0; kb < 4; kb++){
      half8 z;
      #pragma unroll
      for(int q = 0; q < 8; q++) z[q] = (_Float16)0.f;
      if(rv) z = *(const half8*)&A[(size_t)arow*128 + kb*32 + q4*8];
      ah[kb] = z;
    }
  } else {
    const float* A = (const float*)Av;
    #pragma unroll
    for(int kb = 0; kb < 4; kb++){
      float4 f0 = make_float4(0.f,0.f,0.f,0.f), f1 = f0;
      if(rv){
        f0 = ((const float4*)A)[(size_t)arow*32 + kb*8 + q4*2];
        f1 = ((const float4*)A)[(size_t)arow*32 + kb*8 + q4*2 + 1];
      }
      float fv[8] = {f0.x,f0.y,f0.z,f0.w,f1.x,f1.y,f1.z,f1.w};
      #pragma unroll
      for(int q = 0; q < 8; q++){
        _Float16 h = (_Float16)fv[q];
        ah[kb][q] = h;
        al[kb][q] = (_Float16)(fv[q] - (float)h);
      }
    }
  }

  floatx4 acc[CT];
  #pragma unroll
  for(int ct = 0; ct < CT; ct++) acc[ct] = (floatx4){0.f,0.f,0.f,0.f};

  #pragma unroll
  for(int ct = 0; ct < CT; ct++){
    int wrow = ct*16 + l15;
    #pragma unroll
    for(int kb = 0; kb < 4; kb++){
      int off = wrow*128 + kb*32 + q4*8;
      half8 bh = *(const half8*)&Wh[off];
      half8 bl = *(const half8*)&Wl[off];
      acc[ct] = __builtin_amdgcn_mfma_f32_16x16x32_f16(ah[kb], bh, acc[ct], 0, 0, 0);
      if constexpr (!AHALF)
        acc[ct] = __builtin_amdgcn_mfma_f32_16x16x32_f16(al[kb], bh, acc[ct], 0, 0, 0);
      acc[ct] = __builtin_amdgcn_mfma_f32_16x16x32_f16(ah[kb], bl, acc[ct], 0, 0, 0);
    }
  }

  // epilogue: fused alpha projections + fp16 store
  float s1[4] = {0.f,0.f,0.f,0.f}, s2[4] = {0.f,0.f,0.f,0.f};
  #pragma unroll
  for(int ct = 0; ct < CT; ct++){
    int col = ct*16 + l15;
    float as_c = a_src[col], ad_c = a_dst[col];
    #pragma unroll
    for(int r = 0; r < 4; r++){
      float v = acc[ct][r];
      s1[r] += v*as_c; s2[r] += v*ad_c;
    }
  }
  #pragma unroll
  for(int r = 0; r < 4; r++){
    #pragma unroll
    for(int off = 1; off < 16; off <<= 1){
      s1[r] += __shfl_xor(s1[r], off);
      s2[r] += __shfl_xor(s2[r], off);
    }
  }
  int rowbase = blockIdx.x*64 + w*16 + q4*4;
  if(l15 == 0){
    #pragma unroll
    for(int r = 0; r < 4; r++){
      int g = rowbase + r;
      if(g < N){ aS[g] = s1[r]; aD[g] = s2[r]; }
    }
  }
  #pragma unroll
  for(int ct = 0; ct < CT; ct++){
    #pragma unroll
    for(int r = 0; r < 4; r++){
      int g = rowbase + r;
      if(g < N) h16[(size_t)g*FO + ct*16 + l15] = __float2half(acc[ct][r]);
    }
  }
}

// ---------------- per-dst softmax + weighted aggregation (fp16 payload) ----------------
// Static 8-group fully-unrolled gather: all loads in flight (one latency round per dst).
// Invalid slots have weight exactly 0 and gather row 0 (L1-hot) — no divergence.

template<int F, int ACT, typename OT>
__global__ __launch_bounds__(256) void agg_kernel(const __half* __restrict__ h16,
                                                  const int* __restrict__ row_ptr,
                                                  const int* __restrict__ csr_src,
                                                  const float* __restrict__ aS,
                                                  const float* __restrict__ aD,
                                                  const float* __restrict__ bias,
                                                  OT* __restrict__ out, int N){
  int wid = threadIdx.x >> 6, lane = threadIdx.x & 63;
  int d = blockIdx.x*4 + wid;
  if(d >= N) return;
  int start = row_ptr[d], end = row_ptr[d+1];
  int deg = end - start;
  float aDd = aD[d];
  float e_self = lrelu(aS[d] + aDd);

  // chunk 0 (up to 64 edges) in registers: lane i owns slot i
  int i0 = start + lane;
  bool val0 = (i0 < end);
  int idx0 = val0 ? csr_src[i0] : 0;
  float w0 = val0 ? lrelu(aS[idx0] + aDd) : -1e30f;

  float m = fmaxf(e_self, w0);
  for(int i = start + 64 + lane; i < end; i += 64){
    int s = csr_src[i];
    m = fmaxf(m, lrelu(aS[s] + aDd));
  }
  #pragma unroll
  for(int off = 32; off; off >>= 1) m = fmaxf(m, __shfl_xor(m, off));

  float p0 = val0 ? expf(w0 - m) : 0.f;
  float pself = expf(e_self - m);
  float ssum_l = p0 + (lane == 0 ? pself : 0.f);

  constexpr int LPE = F / 8;       // lanes per edge: 16 (F=128) or 8 (F=64)
  constexpr int EPW = 64 / LPE;    // edges per group: 4 or 8
  int sub = lane / LPE;
  int l2  = lane % LPE;
  float acc8[8];
  #pragma unroll
  for(int q = 0; q < 8; q++) acc8[q] = 0.f;

  auto gat = [&](int s, float wgt){
    union { float4 f4; __half2 h2[4]; } u;
    u.f4 = *(const float4*)&h16[(size_t)s*F + l2*8];
    #pragma unroll
    for(int q = 0; q < 4; q++){
      float2 f = __half22float2(u.h2[q]);
      acc8[2*q]   += wgt*f.x;
      acc8[2*q+1] += wgt*f.y;
    }
  };

  // static groups: slots 0..8*EPW-1 (F=128: 0..31 — covers deg<=32; F=64: all 64)
  #pragma unroll
  for(int g = 0; g < 8; g++){
    int slot = g*EPW + sub;
    int   s   = __shfl(idx0, slot);
    float wgt = __shfl(p0, slot);
    gat(s, wgt);
  }
  // residual slots in chunk 0 (F=128, deg>32 — rare)
  if(F == 128 && deg > 32){
    int lim = deg < 64 ? deg : 64;
    for(int jj = 32 + sub; jj < lim; jj += EPW){
      int   s   = __shfl(idx0, jj);
      float wgt = __shfl(p0, jj);
      gat(s, wgt);
    }
  }

  // extra chunks (deg > 64 — ultra-rare)
  for(int cb = start + 64; cb < end; cb += 64){
    int i = cb + lane;
    bool v = (i < end);
    int idx = v ? csr_src[i] : 0;
    float p = v ? expf(lrelu(aS[idx] + aDd) - m) : 0.f;
    ssum_l += p;
    int cd = (end - cb) < 64 ? (end - cb) : 64;
    for(int jj = sub; jj < cd; jj += EPW){
      int   s   = __shfl(idx, jj);
      float wgt = __shfl(p, jj);
      gat(s, wgt);
    }
  }

  if(sub == 0) gat(d, pself);

  #pragma unroll
  for(int off = 32; off; off >>= 1) ssum_l += __shfl_xor(ssum_l, off);
  float inv = 1.f / ssum_l;

  #pragma unroll
  for(int off = LPE; off < 64; off <<= 1){
    #pragma unroll
    for(int q = 0; q < 8; q++) acc8[q] += __shfl_xor(acc8[q], off);
  }

  if(lane < LPE){
    float4 bv0 = *(const float4*)&bias[lane*8];
    float4 bv1 = *(const float4*)&bias[lane*8 + 4];
    float v[8];
    v[0]=acc8[0]*inv+bv0.x; v[1]=acc8[1]*inv+bv0.y; v[2]=acc8[2]*inv+bv0.z; v[3]=acc8[3]*inv+bv0.w;
    v[4]=acc8[4]*inv+bv1.x; v[5]=acc8[5]*inv+bv1.y; v[6]=acc8[6]*inv+bv1.z; v[7]=acc8[7]*inv+bv1.w;
    #pragma unroll
    for(int q = 0; q < 8; q++){
      if(ACT == 0) v[q] = fmaxf(v[q], 0.f);
      else         v[q] = 1.f/(1.f + expf(-v[q]));
    }
    if constexpr (sizeof(OT) == 2){
      union { half8 h8; __half2 h2[4]; } pk;
      #pragma unroll
      for(int q = 0; q < 4; q++) pk.h2[q] = __floats2half2_rn(v[2*q], v[2*q+1]);
      *(half8*)&out[(size_t)d*F + lane*8] = pk.h8;
    } else {
      *(float4*)&out[(size_t)d*F + lane*8]     = make_float4(v[0],v[1],v[2],v[3]);
      *(float4*)&out[(size_t)d*F + lane*8 + 4] = make_float4(v[4],v[5],v[6],v[7]);
    }
  }
}

// ---------------- launch ----------------

extern "C" void kernel_launch(void* const* d_in, const int* in_sizes, int n_in,
                              void* d_out, int out_size, void* d_ws, size_t ws_size,
                              hipStream_t stream){
  const float* x   = (const float*)d_in[0];
  const int*   ei  = (const int*)d_in[1];
  const float* W1  = (const float*)d_in[2];
  const float* a1s = (const float*)d_in[3];
  const float* a1d = (const float*)d_in[4];
  const float* b1  = (const float*)d_in[5];
  const float* W2  = (const float*)d_in[6];
  const float* a2s = (const float*)d_in[7];
  const float* a2d = (const float*)d_in[8];
  const float* b2  = (const float*)d_in[9];

  const int Fin = 128, H = 128, F2 = 64;
  int N = in_sizes[0] / Fin;
  int E = in_sizes[1] / 2;
  const int* src = ei;
  const int* dst = ei + E;

  char* w = (char*)d_ws;
  auto carve = [&](size_t bytes) -> void* {
    void* p = (void*)w;
    w += (bytes + 255) & ~(size_t)255;
    return p;
  };
  __half*    h1_16  = (__half*)carve((size_t)N*H*2);
  __half*    h2_16  = (__half*)carve((size_t)N*F2*2);
  __half*    h1a    = (__half*)carve((size_t)N*H*2);   // layer-1 output, fp16
  float*     aS     = (float*)carve((size_t)N*4);
  float*     aD     = (float*)carve((size_t)N*4);
  int*       deg    = (int*)  carve((size_t)N*4);
  int*       row_ptr= (int*)  carve((size_t)(N+1)*4);
  int*       cursor = (int*)  carve((size_t)N*4);
  int*       partials=(int*)  carve((size_t)1024*4);
  int*       csr_src= (int*)  carve((size_t)E*4);
  _Float16*  W1h    = (_Float16*)carve((size_t)128*128*2);
  _Float16*  W1l    = (_Float16*)carve((size_t)128*128*2);
  _Float16*  W2h    = (_Float16*)carve((size_t)64*128*2);
  _Float16*  W2l    = (_Float16*)carve((size_t)64*128*2);
  (void)ws_size; (void)n_in; (void)out_size;

  int nb = (N + 1023) / 1024;
  int npart = (N + 7) / 8;

  // CSR by destination (XCD-partitioned hist/scatter)
  hipMemsetAsync(deg, 0, (size_t)N*4, stream);
  transpose_w<<<96, 256, 0, stream>>>(W1, W2, W1h, W1l, W2h, W2l);
  hist_kernel<<<2048, 256, 0, stream>>>(dst, deg, E, npart);
  block_sums<<<nb, 256, 0, stream>>>(deg, partials, N);
  scan_partials<<<1, 64, 0, stream>>>(partials, nb);
  scan_apply<<<nb, 256, 0, stream>>>(deg, partials, row_ptr, cursor, N, E);
  scatter_kernel<<<2048, 256, 0, stream>>>(src, dst, cursor, csr_src, E, npart);

  // layer 1
  gemm_mfma<128,0><<<(N+63)/64, 256, 0, stream>>>(x, W1h, W1l, a1s, a1d, h1_16, aS, aD, N);
  agg_kernel<128,0,__half><<<(N+3)/4, 256, 0, stream>>>(h1_16, row_ptr, csr_src, aS, aD, b1, h1a, N);

  // layer 2
  gemm_mfma<64,1><<<(N+63)/64, 256, 0, stream>>>(h1a, W2h, W2l, a2s, a2d, h2_16, aS, aD, N);
  agg_kernel<64,1,float><<<(N+3)/4, 256, 0, stream>>>(h2_16, row_ptr, csr_src, aS, aD, b2, (float*)d_out, N);
}

// Round 8
// 227.124 us; speedup vs baseline: 1.8570x; 1.0027x over previous
//
#include <hip/hip_runtime.h>
#include <hip/hip_fp16.h>

#define NEG_SLOPE 0.2f

typedef _Float16 half8 __attribute__((ext_vector_type(8)));
typedef float floatx4 __attribute__((ext_vector_type(4)));

__device__ __forceinline__ float lrelu(float x){ return x > 0.f ? x : NEG_SLOPE*x; }

// ---------------- CSR build (XCD-partitioned: blockIdx%8 -> dst range) ----------------

__global__ __launch_bounds__(256) void hist_kernel(const int* __restrict__ dst,
                                                   int* __restrict__ deg,
                                                   int E, int npart){
  int part = blockIdx.x & 7;
  int w    = blockIdx.x >> 3;
  int lo = part * npart, hi = lo + npart;
  int stride = (gridDim.x >> 3) * 256;
  for(int e = w*256 + threadIdx.x; e < E; e += stride){
    int d = __builtin_nontemporal_load(&dst[e]);
    if(d >= lo && d < hi) atomicAdd(&deg[d], 1);
  }
}

__global__ __launch_bounds__(256) void scatter_kernel(const int* __restrict__ src,
                                                      const int* __restrict__ dst,
                                                      int* __restrict__ cursor,
                                                      int* __restrict__ csr_src,
                                                      int E, int npart){
  int part = blockIdx.x & 7;
  int w    = blockIdx.x >> 3;
  int lo = part * npart, hi = lo + npart;
  int stride = (gridDim.x >> 3) * 256;
  for(int e = w*256 + threadIdx.x; e < E; e += stride){
    int d = __builtin_nontemporal_load(&dst[e]);
    if(d >= lo && d < hi){
      int sv = __builtin_nontemporal_load(&src[e]);
      int p = atomicAdd(&cursor[d], 1);
      csr_src[p] = sv;
    }
  }
}

__global__ __launch_bounds__(256) void block_sums(const int* __restrict__ deg,
                                                  int* __restrict__ partials, int N){
  __shared__ int wsum[4];
  int b = blockIdx.x, tid = threadIdx.x;
  int wid = tid >> 6, lane = tid & 63;
  int i0 = b*1024 + tid*4;
  int s = 0;
  if(i0 + 3 < N){
    int4 t = *(const int4*)&deg[i0];
    s = t.x + t.y + t.z + t.w;
  } else {
    if(i0   < N) s += deg[i0];
    if(i0+1 < N) s += deg[i0+1];
    if(i0+2 < N) s += deg[i0+2];
    if(i0+3 < N) s += deg[i0+3];
  }
  #pragma unroll
  for(int off = 32; off; off >>= 1) s += __shfl_xor(s, off);
  if(lane == 0) wsum[wid] = s;
  __syncthreads();
  if(tid == 0) partials[b] = wsum[0] + wsum[1] + wsum[2] + wsum[3];
}

__global__ void scan_partials(int* __restrict__ partials, int nb){
  int lane = threadIdx.x & 63;
  int base = 0;
  for(int c0 = 0; c0 < nb; c0 += 64){
    int i = c0 + lane;
    int v = (i < nb) ? partials[i] : 0;
    int s = v;
    #pragma unroll
    for(int off = 1; off < 64; off <<= 1){
      int t = __shfl_up(s, off);
      if(lane >= off) s += t;
    }
    if(i < nb) partials[i] = base + s - v;
    base += __shfl(s, 63);
  }
}

__global__ __launch_bounds__(256) void scan_apply(const int* __restrict__ deg,
                                                  const int* __restrict__ partials,
                                                  int* __restrict__ row_ptr,
                                                  int* __restrict__ cursor, int N, int E){
  __shared__ int wsum[4];
  int b = blockIdx.x, tid = threadIdx.x;
  int wid = tid >> 6, lane = tid & 63;
  int i0 = b*1024 + tid*4;
  int v0=0,v1=0,v2=0,v3=0;
  if(i0 + 3 < N){
    int4 t = *(const int4*)&deg[i0];
    v0=t.x; v1=t.y; v2=t.z; v3=t.w;
  } else {
    if(i0   < N) v0 = deg[i0];
    if(i0+1 < N) v1 = deg[i0+1];
    if(i0+2 < N) v2 = deg[i0+2];
    if(i0+3 < N) v3 = deg[i0+3];
  }
  int tot = v0+v1+v2+v3;
  int s = tot;
  #pragma unroll
  for(int off = 1; off < 64; off <<= 1){
    int t = __shfl_up(s, off);
    if(lane >= off) s += t;
  }
  int texcl = s - tot;
  if(lane == 63) wsum[wid] = s;
  __syncthreads();
  int woff = 0;
  for(int w = 0; w < wid; w++) woff += wsum[w];
  int base = partials[b] + woff + texcl;
  if(i0   < N){ row_ptr[i0]   = base;          cursor[i0]   = base; }
  if(i0+1 < N){ row_ptr[i0+1] = base+v0;       cursor[i0+1] = base+v0; }
  if(i0+2 < N){ row_ptr[i0+2] = base+v0+v1;    cursor[i0+2] = base+v0+v1; }
  if(i0+3 < N){ row_ptr[i0+3] = base+v0+v1+v2; cursor[i0+3] = base+v0+v1+v2; }
  if(b == 0 && tid == 0) row_ptr[N] = E;
}

// ---------------- W transpose to fp16 hi/lo (once per launch) ----------------

__global__ void transpose_w(const float* __restrict__ W1, const float* __restrict__ W2,
                            _Float16* __restrict__ W1h, _Float16* __restrict__ W1l,
                            _Float16* __restrict__ W2h, _Float16* __restrict__ W2l){
  int i = blockIdx.x*256 + threadIdx.x;
  if(i < 128*128){
    int k = i >> 7, c = i & 127;
    float f = W1[i];
    _Float16 h = (_Float16)f;
    W1h[c*128 + k] = h;
    W1l[c*128 + k] = (_Float16)(f - (float)h);
  } else if(i < 128*128 + 128*64){
    int j = i - 128*128;
    int k = j >> 6, c = j & 63;
    float f = W2[j];
    _Float16 h = (_Float16)f;
    W2h[c*128 + k] = h;
    W2l[c*128 + k] = (_Float16)(f - (float)h);
  }
}

// ---------------- MFMA GEMM (LDS-free, hi/lo compensated) ----------------
// AHALF=0: A fp32, split hi/lo in-register, 3 MFMAs/tile. AHALF=1: A fp16 exact, 2 MFMAs.

template<int FO, int AHALF>
__global__ __launch_bounds__(256) void gemm_mfma(const void* __restrict__ Av,
                                                 const _Float16* __restrict__ Wh,
                                                 const _Float16* __restrict__ Wl,
                                                 const float* __restrict__ a_src,
                                                 const float* __restrict__ a_dst,
                                                 __half* __restrict__ h16,
                                                 float* __restrict__ aS,
                                                 float* __restrict__ aD, int N){
  constexpr int CT = FO / 16;
  int tid = threadIdx.x;
  int w = tid >> 6, lane = tid & 63;
  int l15 = lane & 15;
  int q4  = lane >> 4;

  int arow = blockIdx.x*64 + w*16 + l15;
  bool rv = arow < N;

  half8 ah[4], al[4];
  if constexpr (AHALF){
    const _Float16* A = (const _Float16*)Av;
    #pragma unroll
    for(int kb = 0; kb < 4; kb++){
      half8 z;
      #pragma unroll
      for(int q = 0; q < 8; q++) z[q] = (_Float16)0.f;
      if(rv) z = *(const half8*)&A[(size_t)arow*128 + kb*32 + q4*8];
      ah[kb] = z;
    }
  } else {
    const float* A = (const float*)Av;
    #pragma unroll
    for(int kb = 0; kb < 4; kb++){
      float4 f0 = make_float4(0.f,0.f,0.f,0.f), f1 = f0;
      if(rv){
        f0 = ((const float4*)A)[(size_t)arow*32 + kb*8 + q4*2];
        f1 = ((const float4*)A)[(size_t)arow*32 + kb*8 + q4*2 + 1];
      }
      float fv[8] = {f0.x,f0.y,f0.z,f0.w,f1.x,f1.y,f1.z,f1.w};
      #pragma unroll
      for(int q = 0; q < 8; q++){
        _Float16 h = (_Float16)fv[q];
        ah[kb][q] = h;
        al[kb][q] = (_Float16)(fv[q] - (float)h);
      }
    }
  }

  floatx4 acc[CT];
  #pragma unroll
  for(int ct = 0; ct < CT; ct++) acc[ct] = (floatx4){0.f,0.f,0.f,0.f};

  #pragma unroll
  for(int ct = 0; ct < CT; ct++){
    int wrow = ct*16 + l15;
    #pragma unroll
    for(int kb = 0; kb < 4; kb++){
      int off = wrow*128 + kb*32 + q4*8;
      half8 bh = *(const half8*)&Wh[off];
      half8 bl = *(const half8*)&Wl[off];
      acc[ct] = __builtin_amdgcn_mfma_f32_16x16x32_f16(ah[kb], bh, acc[ct], 0, 0, 0);
      if constexpr (!AHALF)
        acc[ct] = __builtin_amdgcn_mfma_f32_16x16x32_f16(al[kb], bh, acc[ct], 0, 0, 0);
      acc[ct] = __builtin_amdgcn_mfma_f32_16x16x32_f16(ah[kb], bl, acc[ct], 0, 0, 0);
    }
  }

  // epilogue: fused alpha projections + fp16 store
  float s1[4] = {0.f,0.f,0.f,0.f}, s2[4] = {0.f,0.f,0.f,0.f};
  #pragma unroll
  for(int ct = 0; ct < CT; ct++){
    int col = ct*16 + l15;
    float as_c = a_src[col], ad_c = a_dst[col];
    #pragma unroll
    for(int r = 0; r < 4; r++){
      float v = acc[ct][r];
      s1[r] += v*as_c; s2[r] += v*ad_c;
    }
  }
  #pragma unroll
  for(int r = 0; r < 4; r++){
    #pragma unroll
    for(int off = 1; off < 16; off <<= 1){
      s1[r] += __shfl_xor(s1[r], off);
      s2[r] += __shfl_xor(s2[r], off);
    }
  }
  int rowbase = blockIdx.x*64 + w*16 + q4*4;
  if(l15 == 0){
    #pragma unroll
    for(int r = 0; r < 4; r++){
      int g = rowbase + r;
      if(g < N){ aS[g] = s1[r]; aD[g] = s2[r]; }
    }
  }
  #pragma unroll
  for(int ct = 0; ct < CT; ct++){
    #pragma unroll
    for(int r = 0; r < 4; r++){
      int g = rowbase + r;
      if(g < N) h16[(size_t)g*FO + ct*16 + l15] = __float2half(acc[ct][r]);
    }
  }
}

// ---------------- per-dst softmax + weighted aggregation (fp16 payload) ----------------
// Packed fp16 accumulation: v_pk_fma_f16 (2 feats/op, no cvt). Softmax weights fp32.
// Dynamic exact-trip gather loops (no wasted slots).

template<int F, int ACT, typename OT>
__global__ __launch_bounds__(256) void agg_kernel(const __half* __restrict__ h16,
                                                  const int* __restrict__ row_ptr,
                                                  const int* __restrict__ csr_src,
                                                  const float* __restrict__ aS,
                                                  const float* __restrict__ aD,
                                                  const float* __restrict__ bias,
                                                  OT* __restrict__ out, int N){
  int wid = threadIdx.x >> 6, lane = threadIdx.x & 63;
  int d = blockIdx.x*4 + wid;
  if(d >= N) return;
  int start = row_ptr[d], end = row_ptr[d+1];
  int deg = end - start;
  float aDd = aD[d];
  float e_self = lrelu(aS[d] + aDd);

  // chunk 0 (up to 64 edges) in registers: lane i owns slot i
  int i0 = start + lane;
  bool val0 = (i0 < end);
  int idx0 = val0 ? csr_src[i0] : 0;
  float w0 = val0 ? lrelu(aS[idx0] + aDd) : -1e30f;

  float m = fmaxf(e_self, w0);
  for(int i = start + 64 + lane; i < end; i += 64){
    int s = csr_src[i];
    m = fmaxf(m, lrelu(aS[s] + aDd));
  }
  #pragma unroll
  for(int off = 32; off; off >>= 1) m = fmaxf(m, __shfl_xor(m, off));

  float p0 = val0 ? expf(w0 - m) : 0.f;
  float pself = expf(e_self - m);
  float ssum_l = p0 + (lane == 0 ? pself : 0.f);

  constexpr int LPE = F / 8;       // lanes per edge: 16 (F=128) or 8 (F=64)
  constexpr int EPW = 64 / LPE;    // edges per group: 4 or 8
  int sub = lane / LPE;
  int l2  = lane % LPE;

  __half2 hacc[4];
  #pragma unroll
  for(int q = 0; q < 4; q++) hacc[q] = __floats2half2_rn(0.f, 0.f);

  auto gat = [&](int s, float wgt){
    union { float4 f4; __half2 h2[4]; } u;
    u.f4 = *(const float4*)&h16[(size_t)s*F + l2*8];
    __half2 w2 = __float2half2_rn(wgt);
    #pragma unroll
    for(int q = 0; q < 4; q++) hacc[q] = __hfma2(w2, u.h2[q], hacc[q]);
  };

  int c0deg = deg < 64 ? deg : 64;
  #pragma unroll 4
  for(int jj = sub; jj < c0deg; jj += EPW){
    int   s   = __shfl(idx0, jj);
    float wgt = __shfl(p0, jj);
    gat(s, wgt);
  }

  // extra chunks (deg > 64 — ultra-rare)
  for(int cb = start + 64; cb < end; cb += 64){
    int i = cb + lane;
    bool v = (i < end);
    int idx = v ? csr_src[i] : 0;
    float p = v ? expf(lrelu(aS[idx] + aDd) - m) : 0.f;
    ssum_l += p;
    int cd = (end - cb) < 64 ? (end - cb) : 64;
    for(int jj = sub; jj < cd; jj += EPW){
      int   s   = __shfl(idx, jj);
      float wgt = __shfl(p, jj);
      gat(s, wgt);
    }
  }

  if(sub == 0) gat(d, pself);

  #pragma unroll
  for(int off = 32; off; off >>= 1) ssum_l += __shfl_xor(ssum_l, off);
  float inv = 1.f / ssum_l;

  // combine sub-waves (packed fp16 adds)
  #pragma unroll
  for(int off = LPE; off < 64; off <<= 1){
    #pragma unroll
    for(int q = 0; q < 4; q++){
      union { __half2 h; int i; } a, b;
      a.h = hacc[q];
      b.i = __shfl_xor(a.i, off);
      hacc[q] = __hadd2(a.h, b.h);
    }
  }

  if(lane < LPE){
    float4 bv0 = *(const float4*)&bias[lane*8];
    float4 bv1 = *(const float4*)&bias[lane*8 + 4];
    float v[8];
    #pragma unroll
    for(int q = 0; q < 4; q++){
      float2 f = __half22float2(hacc[q]);
      v[2*q]   = f.x*inv;
      v[2*q+1] = f.y*inv;
    }
    v[0]+=bv0.x; v[1]+=bv0.y; v[2]+=bv0.z; v[3]+=bv0.w;
    v[4]+=bv1.x; v[5]+=bv1.y; v[6]+=bv1.z; v[7]+=bv1.w;
    #pragma unroll
    for(int q = 0; q < 8; q++){
      if(ACT == 0) v[q] = fmaxf(v[q], 0.f);
      else         v[q] = 1.f/(1.f + expf(-v[q]));
    }
    if constexpr (sizeof(OT) == 2){
      union { half8 h8; __half2 h2[4]; } pk;
      #pragma unroll
      for(int q = 0; q < 4; q++) pk.h2[q] = __floats2half2_rn(v[2*q], v[2*q+1]);
      *(half8*)&out[(size_t)d*F + lane*8] = pk.h8;
    } else {
      *(float4*)&out[(size_t)d*F + lane*8]     = make_float4(v[0],v[1],v[2],v[3]);
      *(float4*)&out[(size_t)d*F + lane*8 + 4] = make_float4(v[4],v[5],v[6],v[7]);
    }
  }
}

// ---------------- launch ----------------

extern "C" void kernel_launch(void* const* d_in, const int* in_sizes, int n_in,
                              void* d_out, int out_size, void* d_ws, size_t ws_size,
                              hipStream_t stream){
  const float* x   = (const float*)d_in[0];
  const int*   ei  = (const int*)d_in[1];
  const float* W1  = (const float*)d_in[2];
  const float* a1s = (const float*)d_in[3];
  const float* a1d = (const float*)d_in[4];
  const float* b1  = (const float*)d_in[5];
  const float* W2  = (const float*)d_in[6];
  const float* a2s = (const float*)d_in[7];
  const float* a2d = (const float*)d_in[8];
  const float* b2  = (const float*)d_in[9];

  const int Fin = 128, H = 128, F2 = 64;
  int N = in_sizes[0] / Fin;
  int E = in_sizes[1] / 2;
  const int* src = ei;
  const int* dst = ei + E;

  char* w = (char*)d_ws;
  auto carve = [&](size_t bytes) -> void* {
    void* p = (void*)w;
    w += (bytes + 255) & ~(size_t)255;
    return p;
  };
  __half*    h1_16  = (__half*)carve((size_t)N*H*2);
  __half*    h2_16  = (__half*)carve((size_t)N*F2*2);
  __half*    h1a    = (__half*)carve((size_t)N*H*2);   // layer-1 output, fp16
  float*     aS     = (float*)carve((size_t)N*4);
  float*     aD     = (float*)carve((size_t)N*4);
  int*       deg    = (int*)  carve((size_t)N*4);
  int*       row_ptr= (int*)  carve((size_t)(N+1)*4);
  int*       cursor = (int*)  carve((size_t)N*4);
  int*       partials=(int*)  carve((size_t)1024*4);
  int*       csr_src= (int*)  carve((size_t)E*4);
  _Float16*  W1h    = (_Float16*)carve((size_t)128*128*2);
  _Float16*  W1l    = (_Float16*)carve((size_t)128*128*2);
  _Float16*  W2h    = (_Float16*)carve((size_t)64*128*2);
  _Float16*  W2l    = (_Float16*)carve((size_t)64*128*2);
  (void)ws_size; (void)n_in; (void)out_size;

  int nb = (N + 1023) / 1024;
  int npart = (N + 7) / 8;

  // CSR by destination (XCD-partitioned hist/scatter)
  hipMemsetAsync(deg, 0, (size_t)N*4, stream);
  transpose_w<<<96, 256, 0, stream>>>(W1, W2, W1h, W1l, W2h, W2l);
  hist_kernel<<<2048, 256, 0, stream>>>(dst, deg, E, npart);
  block_sums<<<nb, 256, 0, stream>>>(deg, partials, N);
  scan_partials<<<1, 64, 0, stream>>>(partials, nb);
  scan_apply<<<nb, 256, 0, stream>>>(deg, partials, row_ptr, cursor, N, E);
  scatter_kernel<<<2048, 256, 0, stream>>>(src, dst, cursor, csr_src, E, npart);

  // layer 1
  gemm_mfma<128,0><<<(N+63)/64, 256, 0, stream>>>(x, W1h, W1l, a1s, a1d, h1_16, aS, aD, N);
  agg_kernel<128,0,__half><<<(N+3)/4, 256, 0, stream>>>(h1_16, row_ptr, csr_src, aS, aD, b1, h1a, N);

  // layer 2
  gemm_mfma<64,1><<<(N+63)/64, 256, 0, stream>>>(h1a, W2h, W2l, a2s, a2d, h2_16, aS, aD, N);
  agg_kernel<64,1,float><<<(N+3)/4, 256, 0, stream>>>(h2_16, row_ptr, csr_src, aS, aD, b2, (float*)d_out, N);
}

// Round 9
// 217.775 us; speedup vs baseline: 1.9367x; 1.0429x over previous
//
#include <hip/hip_runtime.h>
#include <hip/hip_fp16.h>

#define NEG_SLOPE 0.2f

typedef _Float16 half8 __attribute__((ext_vector_type(8)));
typedef float floatx4 __attribute__((ext_vector_type(4)));

__device__ __forceinline__ float lrelu(float x){ return x > 0.f ? x : NEG_SLOPE*x; }

// ---------------- CSR build (XCD-partitioned: blockIdx%8 -> dst range) ----------------

__global__ __launch_bounds__(256) void hist_kernel(const int* __restrict__ dst,
                                                   int* __restrict__ deg,
                                                   int E, int npart){
  int part = blockIdx.x & 7;
  int w    = blockIdx.x >> 3;
  int lo = part * npart, hi = lo + npart;
  int stride = (gridDim.x >> 3) * 256;
  for(int e = w*256 + threadIdx.x; e < E; e += stride){
    int d = __builtin_nontemporal_load(&dst[e]);
    if(d >= lo && d < hi) atomicAdd(&deg[d], 1);
  }
}

__global__ __launch_bounds__(256) void scatter_kernel(const int* __restrict__ src,
                                                      const int* __restrict__ dst,
                                                      int* __restrict__ cursor,
                                                      int* __restrict__ csr_src,
                                                      int E, int npart){
  int part = blockIdx.x & 7;
  int w    = blockIdx.x >> 3;
  int lo = part * npart, hi = lo + npart;
  int stride = (gridDim.x >> 3) * 256;
  for(int e = w*256 + threadIdx.x; e < E; e += stride){
    int d = __builtin_nontemporal_load(&dst[e]);
    if(d >= lo && d < hi){
      int sv = __builtin_nontemporal_load(&src[e]);
      int p = atomicAdd(&cursor[d], 1);
      csr_src[p] = sv;
    }
  }
}

__global__ __launch_bounds__(256) void block_sums(const int* __restrict__ deg,
                                                  int* __restrict__ partials, int N){
  __shared__ int wsum[4];
  int b = blockIdx.x, tid = threadIdx.x;
  int wid = tid >> 6, lane = tid & 63;
  int i0 = b*1024 + tid*4;
  int s = 0;
  if(i0 + 3 < N){
    int4 t = *(const int4*)&deg[i0];
    s = t.x + t.y + t.z + t.w;
  } else {
    if(i0   < N) s += deg[i0];
    if(i0+1 < N) s += deg[i0+1];
    if(i0+2 < N) s += deg[i0+2];
    if(i0+3 < N) s += deg[i0+3];
  }
  #pragma unroll
  for(int off = 32; off; off >>= 1) s += __shfl_xor(s, off);
  if(lane == 0) wsum[wid] = s;
  __syncthreads();
  if(tid == 0) partials[b] = wsum[0] + wsum[1] + wsum[2] + wsum[3];
}

__global__ void scan_partials(int* __restrict__ partials, int nb){
  int lane = threadIdx.x & 63;
  int base = 0;
  for(int c0 = 0; c0 < nb; c0 += 64){
    int i = c0 + lane;
    int v = (i < nb) ? partials[i] : 0;
    int s = v;
    #pragma unroll
    for(int off = 1; off < 64; off <<= 1){
      int t = __shfl_up(s, off);
      if(lane >= off) s += t;
    }
    if(i < nb) partials[i] = base + s - v;
    base += __shfl(s, 63);
  }
}

__global__ __launch_bounds__(256) void scan_apply(const int* __restrict__ deg,
                                                  const int* __restrict__ partials,
                                                  int* __restrict__ row_ptr,
                                                  int* __restrict__ cursor, int N, int E){
  __shared__ int wsum[4];
  int b = blockIdx.x, tid = threadIdx.x;
  int wid = tid >> 6, lane = tid & 63;
  int i0 = b*1024 + tid*4;
  int v0=0,v1=0,v2=0,v3=0;
  if(i0 + 3 < N){
    int4 t = *(const int4*)&deg[i0];
    v0=t.x; v1=t.y; v2=t.z; v3=t.w;
  } else {
    if(i0   < N) v0 = deg[i0];
    if(i0+1 < N) v1 = deg[i0+1];
    if(i0+2 < N) v2 = deg[i0+2];
    if(i0+3 < N) v3 = deg[i0+3];
  }
  int tot = v0+v1+v2+v3;
  int s = tot;
  #pragma unroll
  for(int off = 1; off < 64; off <<= 1){
    int t = __shfl_up(s, off);
    if(lane >= off) s += t;
  }
  int texcl = s - tot;
  if(lane == 63) wsum[wid] = s;
  __syncthreads();
  int woff = 0;
  for(int w = 0; w < wid; w++) woff += wsum[w];
  int base = partials[b] + woff + texcl;
  if(i0   < N){ row_ptr[i0]   = base;          cursor[i0]   = base; }
  if(i0+1 < N){ row_ptr[i0+1] = base+v0;       cursor[i0+1] = base+v0; }
  if(i0+2 < N){ row_ptr[i0+2] = base+v0+v1;    cursor[i0+2] = base+v0+v1; }
  if(i0+3 < N){ row_ptr[i0+3] = base+v0+v1+v2; cursor[i0+3] = base+v0+v1+v2; }
  if(b == 0 && tid == 0) row_ptr[N] = E;
}

// ---------------- W transpose to fp16 hi/lo + deg zeroing (replaces hipMemsetAsync) ----------------

__global__ void transpose_w(const float* __restrict__ W1, const float* __restrict__ W2,
                            _Float16* __restrict__ W1h, _Float16* __restrict__ W1l,
                            _Float16* __restrict__ W2h, _Float16* __restrict__ W2l,
                            int* __restrict__ deg, int N){
  int i = blockIdx.x*256 + threadIdx.x;
  if(i < 128*128){
    int k = i >> 7, c = i & 127;
    float f = W1[i];
    _Float16 h = (_Float16)f;
    W1h[c*128 + k] = h;
    W1l[c*128 + k] = (_Float16)(f - (float)h);
  } else if(i < 128*128 + 128*64){
    int j = i - 128*128;
    int k = j >> 6, c = j & 63;
    float f = W2[j];
    _Float16 h = (_Float16)f;
    W2h[c*128 + k] = h;
    W2l[c*128 + k] = (_Float16)(f - (float)h);
  }
  // zero deg[] (grid-stride)
  int nt = gridDim.x * 256;
  for(int j = i; j < N; j += nt) deg[j] = 0;
}

// ---------------- MFMA GEMM (LDS-free, hi/lo compensated) ----------------
// AHALF=0: A fp32, split hi/lo in-register, 3 MFMAs/tile. AHALF=1: A fp16 exact, 2 MFMAs.

template<int FO, int AHALF>
__global__ __launch_bounds__(256) void gemm_mfma(const void* __restrict__ Av,
                                                 const _Float16* __restrict__ Wh,
                                                 const _Float16* __restrict__ Wl,
                                                 const float* __restrict__ a_src,
                                                 const float* __restrict__ a_dst,
                                                 __half* __restrict__ h16,
                                                 float* __restrict__ aS,
                                                 float* __restrict__ aD, int N){
  constexpr int CT = FO / 16;
  int tid = threadIdx.x;
  int w = tid >> 6, lane = tid & 63;
  int l15 = lane & 15;
  int q4  = lane >> 4;

  int arow = blockIdx.x*64 + w*16 + l15;
  bool rv = arow < N;

  half8 ah[4], al[4];
  if constexpr (AHALF){
    const _Float16* A = (const _Float16*)Av;
    #pragma unroll
    for(int kb = 0; kb < 4; kb++){
      half8 z;
      #pragma unroll
      for(int q = 0; q < 8; q++) z[q] = (_Float16)0.f;
      if(rv) z = *(const half8*)&A[(size_t)arow*128 + kb*32 + q4*8];
      ah[kb] = z;
    }
  } else {
    const float* A = (const float*)Av;
    #pragma unroll
    for(int kb = 0; kb < 4; kb++){
      float4 f0 = make_float4(0.f,0.f,0.f,0.f), f1 = f0;
      if(rv){
        f0 = ((const float4*)A)[(size_t)arow*32 + kb*8 + q4*2];
        f1 = ((const float4*)A)[(size_t)arow*32 + kb*8 + q4*2 + 1];
      }
      float fv[8] = {f0.x,f0.y,f0.z,f0.w,f1.x,f1.y,f1.z,f1.w};
      #pragma unroll
      for(int q = 0; q < 8; q++){
        _Float16 h = (_Float16)fv[q];
        ah[kb][q] = h;
        al[kb][q] = (_Float16)(fv[q] - (float)h);
      }
    }
  }

  floatx4 acc[CT];
  #pragma unroll
  for(int ct = 0; ct < CT; ct++) acc[ct] = (floatx4){0.f,0.f,0.f,0.f};

  #pragma unroll
  for(int ct = 0; ct < CT; ct++){
    int wrow = ct*16 + l15;
    #pragma unroll
    for(int kb = 0; kb < 4; kb++){
      int off = wrow*128 + kb*32 + q4*8;
      half8 bh = *(const half8*)&Wh[off];
      half8 bl = *(const half8*)&Wl[off];
      acc[ct] = __builtin_amdgcn_mfma_f32_16x16x32_f16(ah[kb], bh, acc[ct], 0, 0, 0);
      if constexpr (!AHALF)
        acc[ct] = __builtin_amdgcn_mfma_f32_16x16x32_f16(al[kb], bh, acc[ct], 0, 0, 0);
      acc[ct] = __builtin_amdgcn_mfma_f32_16x16x32_f16(ah[kb], bl, acc[ct], 0, 0, 0);
    }
  }

  // epilogue: fused alpha projections + fp16 store
  float s1[4] = {0.f,0.f,0.f,0.f}, s2[4] = {0.f,0.f,0.f,0.f};
  #pragma unroll
  for(int ct = 0; ct < CT; ct++){
    int col = ct*16 + l15;
    float as_c = a_src[col], ad_c = a_dst[col];
    #pragma unroll
    for(int r = 0; r < 4; r++){
      float v = acc[ct][r];
      s1[r] += v*as_c; s2[r] += v*ad_c;
    }
  }
  #pragma unroll
  for(int r = 0; r < 4; r++){
    #pragma unroll
    for(int off = 1; off < 16; off <<= 1){
      s1[r] += __shfl_xor(s1[r], off);
      s2[r] += __shfl_xor(s2[r], off);
    }
  }
  int rowbase = blockIdx.x*64 + w*16 + q4*4;
  if(l15 == 0){
    #pragma unroll
    for(int r = 0; r < 4; r++){
      int g = rowbase + r;
      if(g < N){ aS[g] = s1[r]; aD[g] = s2[r]; }
    }
  }
  #pragma unroll
  for(int ct = 0; ct < CT; ct++){
    #pragma unroll
    for(int r = 0; r < 4; r++){
      int g = rowbase + r;
      if(g < N) h16[(size_t)g*FO + ct*16 + l15] = __float2half(acc[ct][r]);
    }
  }
}

// ---------------- per-dst softmax + weighted aggregation (fp16 payload) ----------------
// Packed fp16 accumulation (v_pk_fma_f16); (idx,wgt) staged once per wave in LDS,
// gather reads one ds_read_b64 per edge (replaces 2 ds_bpermute).

template<int F, int ACT, typename OT>
__global__ __launch_bounds__(256) void agg_kernel(const __half* __restrict__ h16,
                                                  const int* __restrict__ row_ptr,
                                                  const int* __restrict__ csr_src,
                                                  const float* __restrict__ aS,
                                                  const float* __restrict__ aD,
                                                  const float* __restrict__ bias,
                                                  OT* __restrict__ out, int N){
  __shared__ int2 sw[4][64];
  int wid = threadIdx.x >> 6, lane = threadIdx.x & 63;
  int d = blockIdx.x*4 + wid;
  if(d >= N) return;
  int start = row_ptr[d], end = row_ptr[d+1];
  int deg = end - start;
  float aDd = aD[d];
  float e_self = lrelu(aS[d] + aDd);

  // chunk 0 (up to 64 edges): lane i owns slot i
  int i0 = start + lane;
  bool val0 = (i0 < end);
  int idx0 = val0 ? csr_src[i0] : 0;
  float w0 = val0 ? lrelu(aS[idx0] + aDd) : -1e30f;

  float m = fmaxf(e_self, w0);
  for(int i = start + 64 + lane; i < end; i += 64){
    int s = csr_src[i];
    m = fmaxf(m, lrelu(aS[s] + aDd));
  }
  #pragma unroll
  for(int off = 32; off; off >>= 1) m = fmaxf(m, __shfl_xor(m, off));

  float p0 = val0 ? __expf(w0 - m) : 0.f;
  float pself = __expf(e_self - m);
  float ssum_l = p0 + (lane == 0 ? pself : 0.f);

  // stage (idx, wgt) in LDS — wave-local; the shfl-reduce above (6 DS ops)
  // plus the in-order LDS pipeline guarantees visibility before the reads below.
  sw[wid][lane] = make_int2(idx0, __float_as_int(p0));

  constexpr int LPE = F / 8;       // lanes per edge: 16 (F=128) or 8 (F=64)
  constexpr int EPW = 64 / LPE;    // edges per group: 4 or 8
  int sub = lane / LPE;
  int l2  = lane % LPE;

  __half2 hacc[4];
  #pragma unroll
  for(int q = 0; q < 4; q++) hacc[q] = __floats2half2_rn(0.f, 0.f);

  auto gat = [&](int s, float wgt){
    union { float4 f4; __half2 h2[4]; } u;
    u.f4 = *(const float4*)&h16[(size_t)s*F + l2*8];
    __half2 w2 = __float2half2_rn(wgt);
    #pragma unroll
    for(int q = 0; q < 4; q++) hacc[q] = __hfma2(w2, u.h2[q], hacc[q]);
  };

  int c0deg = deg < 64 ? deg : 64;
  #pragma unroll 4
  for(int jj = sub; jj < c0deg; jj += EPW){
    int2 iw = sw[wid][jj];
    gat(iw.x, __int_as_float(iw.y));
  }

  // extra chunks (deg > 64 — ultra-rare): shfl path
  for(int cb = start + 64; cb < end; cb += 64){
    int i = cb + lane;
    bool v = (i < end);
    int idx = v ? csr_src[i] : 0;
    float p = v ? __expf(lrelu(aS[idx] + aDd) - m) : 0.f;
    ssum_l += p;
    int cd = (end - cb) < 64 ? (end - cb) : 64;
    for(int jj = sub; jj < cd; jj += EPW){
      int   s   = __shfl(idx, jj);
      float wgt = __shfl(p, jj);
      gat(s, wgt);
    }
  }

  if(sub == 0) gat(d, pself);

  #pragma unroll
  for(int off = 32; off; off >>= 1) ssum_l += __shfl_xor(ssum_l, off);
  float inv = 1.f / ssum_l;

  // combine sub-waves (packed fp16 adds)
  #pragma unroll
  for(int off = LPE; off < 64; off <<= 1){
    #pragma unroll
    for(int q = 0; q < 4; q++){
      union { __half2 h; int i; } a, b;
      a.h = hacc[q];
      b.i = __shfl_xor(a.i, off);
      hacc[q] = __hadd2(a.h, b.h);
    }
  }

  if(lane < LPE){
    float4 bv0 = *(const float4*)&bias[lane*8];
    float4 bv1 = *(const float4*)&bias[lane*8 + 4];
    float v[8];
    #pragma unroll
    for(int q = 0; q < 4; q++){
      float2 f = __half22float2(hacc[q]);
      v[2*q]   = f.x*inv;
      v[2*q+1] = f.y*inv;
    }
    v[0]+=bv0.x; v[1]+=bv0.y; v[2]+=bv0.z; v[3]+=bv0.w;
    v[4]+=bv1.x; v[5]+=bv1.y; v[6]+=bv1.z; v[7]+=bv1.w;
    #pragma unroll
    for(int q = 0; q < 8; q++){
      if(ACT == 0) v[q] = fmaxf(v[q], 0.f);
      else         v[q] = 1.f/(1.f + __expf(-v[q]));
    }
    if constexpr (sizeof(OT) == 2){
      union { half8 h8; __half2 h2[4]; } pk;
      #pragma unroll
      for(int q = 0; q < 4; q++) pk.h2[q] = __floats2half2_rn(v[2*q], v[2*q+1]);
      *(half8*)&out[(size_t)d*F + lane*8] = pk.h8;
    } else {
      *(float4*)&out[(size_t)d*F + lane*8]     = make_float4(v[0],v[1],v[2],v[3]);
      *(float4*)&out[(size_t)d*F + lane*8 + 4] = make_float4(v[4],v[5],v[6],v[7]);
    }
  }
}

// ---------------- launch ----------------

extern "C" void kernel_launch(void* const* d_in, const int* in_sizes, int n_in,
                              void* d_out, int out_size, void* d_ws, size_t ws_size,
                              hipStream_t stream){
  const float* x   = (const float*)d_in[0];
  const int*   ei  = (const int*)d_in[1];
  const float* W1  = (const float*)d_in[2];
  const float* a1s = (const float*)d_in[3];
  const float* a1d = (const float*)d_in[4];
  const float* b1  = (const float*)d_in[5];
  const float* W2  = (const float*)d_in[6];
  const float* a2s = (const float*)d_in[7];
  const float* a2d = (const float*)d_in[8];
  const float* b2  = (const float*)d_in[9];

  const int Fin = 128, H = 128, F2 = 64;
  int N = in_sizes[0] / Fin;
  int E = in_sizes[1] / 2;
  const int* src = ei;
  const int* dst = ei + E;

  char* w = (char*)d_ws;
  auto carve = [&](size_t bytes) -> void* {
    void* p = (void*)w;
    w += (bytes + 255) & ~(size_t)255;
    return p;
  };
  __half*    h1_16  = (__half*)carve((size_t)N*H*2);
  __half*    h2_16  = (__half*)carve((size_t)N*F2*2);
  __half*    h1a    = (__half*)carve((size_t)N*H*2);   // layer-1 output, fp16
  float*     aS     = (float*)carve((size_t)N*4);
  float*     aD     = (float*)carve((size_t)N*4);
  int*       deg    = (int*)  carve((size_t)N*4);
  int*       row_ptr= (int*)  carve((size_t)(N+1)*4);
  int*       cursor = (int*)  carve((size_t)N*4);
  int*       partials=(int*)  carve((size_t)1024*4);
  int*       csr_src= (int*)  carve((size_t)E*4);
  _Float16*  W1h    = (_Float16*)carve((size_t)128*128*2);
  _Float16*  W1l    = (_Float16*)carve((size_t)128*128*2);
  _Float16*  W2h    = (_Float16*)carve((size_t)64*128*2);
  _Float16*  W2l    = (_Float16*)carve((size_t)64*128*2);
  (void)ws_size; (void)n_in; (void)out_size;

  int nb = (N + 1023) / 1024;
  int npart = (N + 7) / 8;

  // CSR by destination (XCD-partitioned hist/scatter); transpose_w also zeroes deg
  transpose_w<<<96, 256, 0, stream>>>(W1, W2, W1h, W1l, W2h, W2l, deg, N);
  hist_kernel<<<2048, 256, 0, stream>>>(dst, deg, E, npart);
  block_sums<<<nb, 256, 0, stream>>>(deg, partials, N);
  scan_partials<<<1, 64, 0, stream>>>(partials, nb);
  scan_apply<<<nb, 256, 0, stream>>>(deg, partials, row_ptr, cursor, N, E);
  scatter_kernel<<<2048, 256, 0, stream>>>(src, dst, cursor, csr_src, E, npart);

  // layer 1
  gemm_mfma<128,0><<<(N+63)/64, 256, 0, stream>>>(x, W1h, W1l, a1s, a1d, h1_16, aS, aD, N);
  agg_kernel<128,0,__half><<<(N+3)/4, 256, 0, stream>>>(h1_16, row_ptr, csr_src, aS, aD, b1, h1a, N);

  // layer 2
  gemm_mfma<64,1><<<(N+63)/64, 256, 0, stream>>>(h1a, W2h, W2l, a2s, a2d, h2_16, aS, aD, N);
  agg_kernel<64,1,float><<<(N+3)/4, 256, 0, stream>>>(h2_16, row_ptr, csr_src, aS, aD, b2, (float*)d_out, N);
}